// Round 14
// baseline (177.810 us; speedup 1.0000x reference)
//
#include <hip/hip_runtime.h>

typedef unsigned short u16;
typedef unsigned int u32;
typedef __attribute__((ext_vector_type(8))) short short8;
typedef __attribute__((ext_vector_type(4))) float f32x4;

#define KD 512
#define HEADS 16
#define DK 32
#define DV 64
#define TT 4096
#define MROWS 8192           // B*T
#define CHUNK 64
#define NCH 64               // T/CHUNK
#define NBH 32               // B*HEADS
#define QSTR 3328            // qkvg row stride (q 0 | k 512 | v 1024 | g 2048 | xg1 3072 | pad to 13*256)
#define SCALE 0.17677669529663687f  // 32^-0.5

__device__ __forceinline__ u16 f2bf(float f) {
    union { float f; unsigned int u; } x; x.f = f;
    unsigned int u = x.u;
    unsigned int r = (u + 0x7fffu + ((u >> 16) & 1u)) >> 16;
    return (u16)r;
}
__device__ __forceinline__ float bf2f(u16 s) {
    union { unsigned int u; float f; } x; x.u = ((unsigned int)s) << 16;
    return x.f;
}
__device__ __forceinline__ void gload16(const u16* g, u16* l) {
    __builtin_amdgcn_global_load_lds((const __attribute__((address_space(1))) u32*)g,
                                     (__attribute__((address_space(3))) u32*)l, 16, 0, 0);
}

// ---------------- fused prep: x cast + weight transposes ----------------
__global__ __launch_bounds__(256) void prep_fused(const float* __restrict__ x,
                                                  u16* __restrict__ xb,
                                                  const float* __restrict__ Wq,
                                                  const float* __restrict__ Wk,
                                                  const float* __restrict__ Wv,
                                                  const float* __restrict__ Wg,
                                                  const float* __restrict__ W1,
                                                  const float* __restrict__ Wo,
                                                  u16* __restrict__ dst) {
    __shared__ float tile[32][33];
    int bid = blockIdx.x;
    if (bid < 8192) {
        int i = bid * 256 + threadIdx.x;
        const float4 v = ((const float4*)x)[i];
        ushort4 o;
        o.x = f2bf(v.x); o.y = f2bf(v.y); o.z = f2bf(v.z); o.w = f2bf(v.w);
        ((ushort4*)xb)[i] = o;
        return;
    }
    int w = bid - 8192;
    int n0 = (w % 136) * 32, k0 = (w / 136) * 32;
    int tx = threadIdx.x & 31, ty = threadIdx.x >> 5;
    int n = n0 + tx;
    const float* src; int sN, cc;
    if (n < 512)       { src = Wq; sN = 512;  cc = n; }
    else if (n < 1024) { src = Wk; sN = 512;  cc = n - 512; }
    else if (n < 2048) { src = Wv; sN = 1024; cc = n - 1024; }
    else if (n < 3072) { src = Wg; sN = 1024; cc = n - 2048; }
    else if (n < 3088) { src = W1; sN = 16;   cc = n - 3072; }
    else if (n < 3328) { src = nullptr; sN = 0; cc = 0; }
    else               { src = Wo; sN = 1024; cc = n - 3328; }
    for (int r = ty; r < 32; r += 8)
        tile[r][tx] = src ? src[(size_t)(k0 + r) * sN + cc] : 0.f;
    __syncthreads();
    for (int r = ty; r < 32; r += 8)
        dst[(size_t)(n0 + r) * 1024 + k0 + tx] = f2bf(tile[tx][r]);
}

// ======================= 6-phase 256x256 GEMM (T2+T3+T4+T5) =======================
#define BARM() do { asm volatile("" ::: "memory"); __builtin_amdgcn_s_barrier(); asm volatile("" ::: "memory"); } while (0)
#define VMW(n) asm volatile("s_waitcnt vmcnt(" #n ")" ::: "memory")

// by-minor XCD mapping: each XCD chunk (52 consecutive wg) spans ~2 B-column panels
// (1 MB, L2-resident) x 32 A-row panels -> B no longer thrashes the 4 MB per-XCD L2.
template<int OUTBF>
__global__ __launch_bounds__(512, 2) void gemm8(const u16* __restrict__ A,
                                                const u16* __restrict__ Bt,
                                                void* __restrict__ C,
                                                int M, int N, int K, int nby) {
    __shared__ u16 SA[2][16384];
    __shared__ u16 SB[2][16384];
    int nwg = gridDim.x, bid = blockIdx.x, cpx = nwg >> 3;
    int wg = (bid & 7) * cpx + (bid >> 3);       // XCD-chunked, bijective (nwg%8==0)
    int bx = wg / nby, by = wg % nby;            // by-minor (see note above)
    int brow = by << 8, bcol = bx << 8;
    int tid = threadIdx.x;
    int wv = tid >> 6, lane = tid & 63;
    int wm = wv >> 2, wn = wv & 3;               // wave -> 128x64 C block
    int l15 = lane & 15, hi = lane >> 4;
    int rxor = l15 & 7;

    int srw = tid >> 3;
    int sg8 = ((tid & 7) ^ (srw & 7)) << 3;
    const u16* aBase = A + (size_t)(brow + srw) * K + sg8;
    const u16* bBase = Bt + (size_t)(bcol + ((tid >> 8) << 6) + (srw & 31)) * K + sg8;

#define STAGE_A(b, h, tt) do { \
        const u16* s_ = aBase + (size_t)(tt) * 64 + (size_t)(h) * 64 * K; \
        gload16(s_,                    &SA[b][(h) * 8192 + tid * 8]); \
        gload16(s_ + (size_t)128 * K,  &SA[b][(h) * 8192 + 4096 + tid * 8]); \
    } while (0)
#define STAGE_B(b, h, tt) do { \
        const u16* s_ = bBase + (size_t)(tt) * 64 + (size_t)(h) * 32 * K; \
        gload16(s_,                    &SB[b][(h) * 8192 + tid * 8]); \
        gload16(s_ + (size_t)128 * K,  &SB[b][(h) * 8192 + 4096 + tid * 8]); \
    } while (0)

    int aRow = (wm * 64 + l15) * 64;
    int bRow = (wn * 32 + l15) * 64;
    int cg0 = (hi ^ rxor) << 3;
    int cg1 = ((4 + hi) ^ rxor) << 3;

#define READ_A(dst, mh, b) do { \
        _Pragma("unroll") \
        for (int mil_ = 0; mil_ < 4; ++mil_) { \
            dst[mil_ * 2 + 0] = *(const short8*)&SA[b][(mh) * 8192 + mil_ * 1024 + aRow + cg0]; \
            dst[mil_ * 2 + 1] = *(const short8*)&SA[b][(mh) * 8192 + mil_ * 1024 + aRow + cg1]; \
        } } while (0)
#define READ_B(dst, nh, b) do { \
        _Pragma("unroll") \
        for (int nil_ = 0; nil_ < 2; ++nil_) { \
            dst[nil_ * 2 + 0] = *(const short8*)&SB[b][(nh) * 8192 + nil_ * 1024 + bRow + cg0]; \
            dst[nil_ * 2 + 1] = *(const short8*)&SB[b][(nh) * 8192 + nil_ * 1024 + bRow + cg1]; \
        } } while (0)

    f32x4 acc[8][4];
    #pragma unroll
    for (int mi = 0; mi < 8; ++mi)
        #pragma unroll
        for (int ni = 0; ni < 4; ++ni)
            acc[mi][ni] = (f32x4){0.f, 0.f, 0.f, 0.f};

#define MM(mb, nb, AF, BF) do { \
        __builtin_amdgcn_s_setprio(1); \
        _Pragma("unroll") \
        for (int ks_ = 0; ks_ < 2; ++ks_) \
        _Pragma("unroll") \
        for (int mil_ = 0; mil_ < 4; ++mil_) \
        _Pragma("unroll") \
        for (int nil_ = 0; nil_ < 2; ++nil_) \
            acc[(mb) + mil_][(nb) + nil_] = __builtin_amdgcn_mfma_f32_16x16x32_bf16( \
                AF[mil_ * 2 + ks_], BF[nil_ * 2 + ks_], acc[(mb) + mil_][(nb) + nil_], 0, 0, 0); \
        __builtin_amdgcn_s_setprio(0); \
    } while (0)

    int NK = K >> 6, NI = NK >> 1;
    STAGE_B(0, 0, 0); STAGE_A(0, 0, 0); STAGE_A(0, 1, 0); STAGE_B(0, 1, 0);
    STAGE_B(1, 0, 1); STAGE_A(1, 0, 1); STAGE_A(1, 1, 1);
    VMW(6);
    BARM();

    short8 alo[8], ahi[8], bb[4];
    for (int i = 0; i < NI; ++i) {
        int ta = 2 * i + 1; if (ta >= NK) ta = NK - 1;
        int tb = 2 * i + 2; if (tb >= NK) tb = NK - 1;
        int tc = 2 * i + 3; if (tc >= NK) tc = NK - 1;
        STAGE_B(1, 1, ta);
        READ_A(alo, 0, 0); READ_B(bb, 0, 0);
        BARM(); MM(0, 0, alo, bb); BARM();
        STAGE_B(0, 0, tb);
        READ_A(ahi, 1, 0);
        BARM(); MM(4, 0, ahi, bb); BARM();
        STAGE_A(0, 0, tb); STAGE_A(0, 1, tb);
        READ_B(bb, 1, 0);
        BARM(); MM(4, 2, ahi, bb); MM(0, 2, alo, bb);
        VMW(8);
        BARM();
        STAGE_B(0, 1, tb);
        READ_A(alo, 0, 1); READ_B(bb, 0, 1);
        BARM(); MM(0, 0, alo, bb); BARM();
        STAGE_B(1, 0, tc);
        READ_A(ahi, 1, 1);
        BARM(); MM(4, 0, ahi, bb);
        VMW(10);
        BARM();
        STAGE_A(1, 0, tc); STAGE_A(1, 1, tc);
        READ_B(bb, 1, 1);
        BARM(); MM(4, 2, ahi, bb); MM(0, 2, alo, bb);
        VMW(6);
        BARM();
    }

    // -------- epilogue: LDS-transposed vectorized store (reuse SA as per-wave slabs) --------
    VMW(0);            // drain the up-to-6 still-in-flight gload_lds targeting SA/SB
    BARM();            // all waves done reading LDS
    if (OUTBF) {
        u16* slab = &SA[0][0] + wv * (16 * 72);
        int r0 = brow + wm * 128;
        int c0 = bcol + wn * 64;
        int row = lane >> 2, colb = (lane & 3) * 8;
        #pragma unroll
        for (int mi = 0; mi < 8; ++mi) {
            #pragma unroll
            for (int ni = 0; ni < 4; ++ni)
                #pragma unroll
                for (int rr = 0; rr < 4; ++rr)
                    slab[(hi * 4 + rr) * 72 + ni * 16 + l15] = f2bf(acc[mi][ni][rr]);
            #pragma unroll
            for (int v = 0; v < 2; ++v) {
                short8 val = *(const short8*)&slab[row * 72 + colb + v * 32];
                *(short8*)((u16*)C + (size_t)(r0 + mi * 16 + row) * N + c0 + colb + v * 32) = val;
            }
        }
    } else {
        int r0 = brow + wm * 128 + (hi << 2);
        int c0 = bcol + wn * 64 + l15;
        #pragma unroll
        for (int mi = 0; mi < 8; ++mi)
            #pragma unroll
            for (int ni = 0; ni < 4; ++ni)
                #pragma unroll
                for (int rr = 0; rr < 4; ++rr)
                    ((float*)C)[(size_t)(r0 + mi * 16 + rr) * N + (c0 + ni * 16)] = acc[mi][ni][rr];
    }
#undef STAGE_A
#undef STAGE_B
#undef READ_A
#undef READ_B
#undef MM
}

// ---------------- 2-phase 128x128 GEMM (N=1024 out-proj: 512 blocks, 5/CU) ----------------
template<int OUTBF>
__global__ __launch_bounds__(256) void gemm_sb(const u16* __restrict__ A,
                                               const u16* __restrict__ Bt,
                                               void* __restrict__ C,
                                               int M, int N, int K, int nbx) {
    __shared__ u16 As[128 * 64];
    __shared__ u16 Bs[128 * 64];
    int nwg = gridDim.x;
    int bid = blockIdx.x;
    int cpx = nwg >> 3;
    int wg = (bid & 7) * cpx + (bid >> 3);
    int bx = wg % nbx, by = wg / nbx;
    int tid = threadIdx.x;
    int wave = tid >> 6, lane = tid & 63;
    int wr = wave >> 1, wc = wave & 1;
    int brow = by * 128, bcol = bx * 128;
    int srow = tid >> 3;
    int sgrp = (tid & 7) ^ (srow & 7);
    const u16* aS = A + (size_t)(brow + srow) * K + sgrp * 8;
    const u16* bS = Bt + (size_t)(bcol + srow) * K + sgrp * 8;
    f32x4 acc[4][4];
    #pragma unroll
    for (int mi = 0; mi < 4; ++mi)
        #pragma unroll
        for (int ni = 0; ni < 4; ++ni)
            acc[mi][ni] = (f32x4){0.f, 0.f, 0.f, 0.f};
    int l15 = lane & 15, hi = lane >> 4;
    int rxor = l15 & 7;
    for (int kt = 0; kt < K; kt += 64) {
        __syncthreads();
        #pragma unroll
        for (int i_ = 0; i_ < 4; ++i_) {
            gload16(aS + (size_t)i_ * 32 * K + kt, As + tid * 8 + i_ * 2048);
            gload16(bS + (size_t)i_ * 32 * K + kt, Bs + tid * 8 + i_ * 2048);
        }
        __syncthreads();
        #pragma unroll
        for (int ks = 0; ks < 2; ++ks) {
            short8 af[4], bfr[4];
            int g = ks * 4 + hi;
            #pragma unroll
            for (int i = 0; i < 4; ++i)
                af[i] = *(const short8*)(As + (size_t)(wr * 64 + i * 16 + l15) * 64 + ((g ^ rxor) << 3));
            #pragma unroll
            for (int i = 0; i < 4; ++i)
                bfr[i] = *(const short8*)(Bs + (size_t)(wc * 64 + i * 16 + l15) * 64 + ((g ^ rxor) << 3));
            #pragma unroll
            for (int mi = 0; mi < 4; ++mi)
                #pragma unroll
                for (int ni = 0; ni < 4; ++ni)
                    acc[mi][ni] = __builtin_amdgcn_mfma_f32_16x16x32_bf16(af[mi], bfr[ni], acc[mi][ni], 0, 0, 0);
        }
    }
    // -------- epilogue --------
    __syncthreads();
    if (!OUTBF) {
        float* slab = (float*)(wave < 2 ? (void*)As : (void*)Bs) + (wave & 1) * (16 * 68);
        int r0 = brow + wr * 64, c0 = bcol + wc * 64;
        int row = lane >> 2, colb = (lane & 3) * 4;
        #pragma unroll
        for (int mi = 0; mi < 4; ++mi) {
            #pragma unroll
            for (int ni = 0; ni < 4; ++ni)
                #pragma unroll
                for (int rr = 0; rr < 4; ++rr)
                    slab[(hi * 4 + rr) * 68 + ni * 16 + l15] = acc[mi][ni][rr];
            #pragma unroll
            for (int v = 0; v < 4; ++v) {
                float4 val = *(const float4*)&slab[row * 68 + colb + v * 16];
                *(float4*)((float*)C + (size_t)(r0 + mi * 16 + row) * N + c0 + colb + v * 16) = val;
            }
        }
    } else {
        u16* slab = As + wave * (16 * 72);
        int r0 = brow + wr * 64, c0 = bcol + wc * 64;
        int row = lane >> 2, colb = (lane & 3) * 8;
        #pragma unroll
        for (int mi = 0; mi < 4; ++mi) {
            #pragma unroll
            for (int ni = 0; ni < 4; ++ni)
                #pragma unroll
                for (int rr = 0; rr < 4; ++rr)
                    slab[(hi * 4 + rr) * 72 + ni * 16 + l15] = f2bf(acc[mi][ni][rr]);
            #pragma unroll
            for (int v = 0; v < 2; ++v) {
                short8 val = *(const short8*)&slab[row * 72 + colb + v * 32];
                *(short8*)((u16*)C + (size_t)(r0 + mi * 16 + row) * N + c0 + colb + v * 32) = val;
            }
        }
    }
}

// ---------------- gate slice: ls[j] = logsigmoid(xg1·W2[:,cc+j] + b2)/16, j=0..7 ----------------
__device__ __forceinline__ void gate_z8(const u16* __restrict__ xg,
                                        const float* __restrict__ W2,
                                        const float* __restrict__ b2,
                                        int cc, float* out8) {
    short8 x0 = *(const short8*)xg;
    short8 x1 = *(const short8*)(xg + 8);
    float z[8];
    float4 z0 = *(const float4*)(b2 + cc);
    float4 z1 = *(const float4*)(b2 + cc + 4);
    z[0]=z0.x; z[1]=z0.y; z[2]=z0.z; z[3]=z0.w;
    z[4]=z1.x; z[5]=z1.y; z[6]=z1.z; z[7]=z1.w;
    #pragma unroll
    for (int u = 0; u < 16; ++u) {
        float xu = bf2f((u16)(u < 8 ? x0[u] : x1[u - 8]));
        const float4 w0 = *(const float4*)(W2 + (size_t)u * 512 + cc);
        const float4 w1 = *(const float4*)(W2 + (size_t)u * 512 + cc + 4);
        z[0] += xu * w0.x; z[1] += xu * w0.y; z[2] += xu * w0.z; z[3] += xu * w0.w;
        z[4] += xu * w1.x; z[5] += xu * w1.y; z[6] += xu * w1.z; z[7] += xu * w1.w;
    }
    #pragma unroll
    for (int j = 0; j < 8; ++j) {
        float zz = z[j];
        out8[j] = (fminf(zz, 0.f) - log1pf(expf(-fabsf(zz)))) * 0.0625f;
    }
}

// ---------------- parallel inclusive cumsum over t (64 rows) of gkS[64][36] ----------------
__device__ __forceinline__ void scan64(float (*gkS)[36], float* Ztot, int tid) {
    int wv2 = tid >> 6, ln = tid & 63;
    #pragma unroll
    for (int ii = 0; ii < 8; ++ii) {
        int i = wv2 * 8 + ii;
        float v = gkS[ln][i];
        #pragma unroll
        for (int d = 1; d < 64; d <<= 1) {
            float u = __shfl_up(v, d);
            if (ln >= d) v += u;
        }
        gkS[ln][i] = v;
        if (Ztot && ln == 63) Ztot[i] = v;
    }
}

// ---------------- phase A (MFMA): gate+cumsum; M^T (bf16) via mfma -> MT, D ----------------
__global__ __launch_bounds__(256) void phaseA(const u16* __restrict__ qkvg,
                                              const float* __restrict__ W2,
                                              const float* __restrict__ b2,
                                              u16* __restrict__ MT_ws,
                                              float* __restrict__ D_ws) {
    int bh = blockIdx.x >> 6, c = blockIdx.x & 63;
    int b = bh >> 4, h = bh & 15;
    int t0 = b * TT + c * CHUNK;
    __shared__ float gkS[64][36];
    __shared__ u16 kdT_bf[32 * 72];
    __shared__ u16 VT_bf[64 * 72];
    __shared__ float Z[32];
    int tid = threadIdx.x;
    int s = tid >> 2, i0 = (tid & 3) << 3;
    {
        float ls[8];
        gate_z8(qkvg + (size_t)(t0 + s) * QSTR + 3072, W2, b2, h * DK + i0, ls);
        #pragma unroll
        for (int jj = 0; jj < 8; ++jj) gkS[s][i0 + jj] = ls[jj];
    }
    short8 kv = *(const short8*)(qkvg + (size_t)(t0 + s) * QSTR + 512 + h * DK + i0);
    {
        int j0 = (tid & 3) << 4;
        short8 v0 = *(const short8*)(qkvg + (size_t)(t0 + s) * QSTR + 1024 + h * DV + j0);
        short8 v1 = *(const short8*)(qkvg + (size_t)(t0 + s) * QSTR + 1024 + h * DV + j0 + 8);
        #pragma unroll
        for (int jj = 0; jj < 8; ++jj) {
            VT_bf[(j0 + jj) * 72 + s] = (u16)v0[jj];
            VT_bf[(j0 + 8 + jj) * 72 + s] = (u16)v1[jj];
        }
    }
    __syncthreads();
    scan64(gkS, Z, tid);
    __syncthreads();
    #pragma unroll
    for (int jj = 0; jj < 8; ++jj)
        kdT_bf[(i0 + jj) * 72 + s] = f2bf(expf(Z[i0 + jj] - gkS[s][i0 + jj]) * bf2f((u16)kv[jj]));
    __syncthreads();
    int wave = tid >> 6, lane = tid & 63, l15 = lane & 15, hi = lane >> 4;
    int it = wave & 1, jp = wave >> 1;
    size_t base = ((size_t)(bh * NCH + c)) * 2048;
    #pragma unroll
    for (int jj2 = 0; jj2 < 2; ++jj2) {
        int jt = jp * 2 + jj2;
        f32x4 mc = (f32x4){0.f, 0.f, 0.f, 0.f};
        #pragma unroll
        for (int kc = 0; kc < 2; ++kc) {
            short8 ak = *(const short8*)&kdT_bf[(it * 16 + l15) * 72 + kc * 32 + hi * 8];
            short8 bv = *(const short8*)&VT_bf[(jt * 16 + l15) * 72 + kc * 32 + hi * 8];
            mc = __builtin_amdgcn_mfma_f32_16x16x32_bf16(ak, bv, mc, 0, 0, 0);
        }
        #pragma unroll
        for (int rr = 0; rr < 4; ++rr)
            MT_ws[base + (size_t)(jt * 16 + l15) * 32 + it * 16 + hi * 4 + rr] = f2bf(mc[rr]);
    }
    if (tid < 32) D_ws[(size_t)(bh * NCH + c) * 32 + tid] = expf(Z[tid]);
}

// ---------------- phase B: chunk-state recurrence, 2 elems/thread, unrolled ----------------
__global__ __launch_bounds__(256) void phaseB(const u16* __restrict__ MT_ws,
                                              const float* __restrict__ D_ws,
                                              u16* __restrict__ HT_ws) {
    int idx = (blockIdx.x * 256 + threadIdx.x) * 2;
    int bh = idx >> 11;
    int ji = idx & 2047;
    int i = ji & 31;
    float h0 = 0.f, h1 = 0.f;
    size_t base = (size_t)bh * NCH * 2048 + ji;
    const float* dp = D_ws + (size_t)bh * NCH * 32 + i;
    #pragma unroll 4
    for (int c = 0; c < NCH; ++c) {
        u32 hp = ((u32)f2bf(h0)) | (((u32)f2bf(h1)) << 16);
        *(u32*)(HT_ws + base + (size_t)c * 2048) = hp;
        float d0 = dp[c * 32], d1 = dp[c * 32 + 1];
        u32 mp = *(const u32*)(MT_ws + base + (size_t)c * 2048);
        h0 = h0 * d0 + bf2f((u16)(mp & 0xffff));
        h1 = h1 * d1 + bf2f((u16)(mp >> 16));
    }
}

// ---------------- phase C (MFMA): score->mask->P, O = P@V + qh@H, fused RMS/swish ----------------
__global__ __launch_bounds__(256) void phaseC(const u16* __restrict__ qkvg,
                                              const float* __restrict__ W2,
                                              const float* __restrict__ b2,
                                              const u16* __restrict__ HT_ws,
                                              const float* __restrict__ gnw,
                                              u16* __restrict__ o_n) {
    int bh = blockIdx.x >> 6, c = blockIdx.x & 63;
    int b = bh >> 4, h = bh & 15;
    int t0 = b * TT + c * CHUNK;
    __shared__ float gkS[64][36];
    __shared__ u16 qh_bf[64 * 40];
    __shared__ u16 kt_bf[64 * 40];
    __shared__ u16 VT_bf[64 * 72];
    __shared__ u16 Ht_bf[64 * 40];
    u16* P_bf = (u16*)&gkS[0][0];
    int tid = threadIdx.x;
    int s = tid >> 2, i0 = (tid & 3) << 3;
    {
        float ls[8];
        gate_z8(qkvg + (size_t)(t0 + s) * QSTR + 3072, W2, b2, h * DK + i0, ls);
        #pragma unroll
        for (int jj = 0; jj < 8; ++jj) gkS[s][i0 + jj] = ls[jj];
    }
    short8 qv = *(const short8*)(qkvg + (size_t)(t0 + s) * QSTR + h * DK + i0);
    short8 kv = *(const short8*)(qkvg + (size_t)(t0 + s) * QSTR + 512 + h * DK + i0);
    {
        int j0 = (tid & 3) << 4;
        short8 v0 = *(const short8*)(qkvg + (size_t)(t0 + s) * QSTR + 1024 + h * DV + j0);
        short8 v1 = *(const short8*)(qkvg + (size_t)(t0 + s) * QSTR + 1024 + h * DV + j0 + 8);
        #pragma unroll
        for (int jj = 0; jj < 8; ++jj) {
            VT_bf[(j0 + jj) * 72 + s] = (u16)v0[jj];
            VT_bf[(j0 + 8 + jj) * 72 + s] = (u16)v1[jj];
        }
    }
    {
        const u16* hp = HT_ws + ((size_t)(bh * NCH + c)) * 2048 + tid * 8;
        short8 hv = *(const short8*)hp;
        int j = tid >> 2, ii0 = (tid & 3) << 3;
        *(short8*)&Ht_bf[j * 40 + ii0] = hv;
    }
    __syncthreads();
    scan64(gkS, nullptr, tid);
    __syncthreads();
    #pragma unroll
    for (int jj = 0; jj < 8; ++jj) {
        float Sv = gkS[s][i0 + jj];
        qh_bf[s * 40 + i0 + jj] = f2bf(bf2f((u16)qv[jj]) * expf(Sv) * SCALE);
        kt_bf[s * 40 + i0 + jj] = f2bf(bf2f((u16)kv[jj]) * expf(fminf(-Sv, 80.f)));
    }
    __syncthreads();
    int wave = tid >> 6, lane = tid & 63, l15 = lane & 15, hi = lane >> 4;
    int w = wave;
    short8 aq = *(const short8*)&qh_bf[(w * 16 + l15) * 40 + hi * 8];
    #pragma unroll
    for (int sn = 0; sn < 4; ++sn) {
        f32x4 sc = (f32x4){0.f, 0.f, 0.f, 0.f};
        if (sn <= w) {
            short8 bk = *(const short8*)&kt_bf[(sn * 16 + l15) * 40 + hi * 8];
            sc = __builtin_amdgcn_mfma_f32_16x16x32_bf16(aq, bk, sc, 0, 0, 0);
        }
        #pragma unroll
        for (int rr = 0; rr < 4; ++rr) {
            float val = sc[rr];
            if (sn > w || (sn == w && l15 > hi * 4 + rr)) val = 0.f;
            P_bf[(w * 16 + hi * 4 + rr) * 72 + sn * 16 + l15] = f2bf(val);
        }
    }
    __syncthreads();
    f32x4 acc[4];
    #pragma unroll
    for (int jn = 0; jn < 4; ++jn) {
        f32x4 a = (f32x4){0.f, 0.f, 0.f, 0.f};
        short8 bhf = *(const short8*)&Ht_bf[(jn * 16 + l15) * 40 + hi * 8];
        acc[jn] = __builtin_amdgcn_mfma_f32_16x16x32_bf16(aq, bhf, a, 0, 0, 0);
    }
    int nkc = (w < 2) ? 1 : 2;
    for (int kc = 0; kc < nkc; ++kc) {
        short8 ap = *(const short8*)&P_bf[(w * 16 + l15) * 72 + kc * 32 + hi * 8];
        #pragma unroll
        for (int jn = 0; jn < 4; ++jn) {
            short8 bv = *(const short8*)&VT_bf[(jn * 16 + l15) * 72 + kc * 32 + hi * 8];
            acc[jn] = __builtin_amdgcn_mfma_f32_16x16x32_bf16(ap, bv, acc[jn], 0, 0, 0);
        }
    }
    #pragma unroll
    for (int rr = 0; rr < 4; ++rr) {
        float sum2 = 0.f;
        #pragma unroll
        for (int jn = 0; jn < 4; ++jn) sum2 += acc[jn][rr] * acc[jn][rr];
        sum2 += __shfl_xor(sum2, 1);
        sum2 += __shfl_xor(sum2, 2);
        sum2 += __shfl_xor(sum2, 4);
        sum2 += __shfl_xor(sum2, 8);
        float rms = rsqrtf(sum2 * (1.f / 64.f) + 1e-5f);
        int t = w * 16 + hi * 4 + rr;
        #pragma unroll
        for (int jn = 0; jn < 4; ++jn) {
            int j = jn * 16 + l15;
            float g = bf2f(qkvg[(size_t)(t0 + t) * QSTR + 2048 + h * DV + j]);
            float sw = g / (1.f + expf(-g));
            float o = acc[jn][rr] * rms * gnw[j] * sw;
            o_n[(size_t)(t0 + t) * 1024 + h * DV + j] = f2bf(o);
        }
    }
}

// ---------------- launch ----------------
extern "C" void kernel_launch(void* const* d_in, const int* in_sizes, int n_in,
                              void* d_out, int out_size, void* d_ws, size_t ws_size,
                              hipStream_t stream) {
    const float* x    = (const float*)d_in[0];
    const float* Wq   = (const float*)d_in[1];
    const float* Wk   = (const float*)d_in[2];
    const float* Wv   = (const float*)d_in[3];
    const float* Wgk1 = (const float*)d_in[4];
    const float* Wgk2 = (const float*)d_in[5];
    const float* bgk2 = (const float*)d_in[6];
    const float* Wg   = (const float*)d_in[7];
    const float* gnw  = (const float*)d_in[8];
    const float* Wo   = (const float*)d_in[9];

    char* ws = (char*)d_ws;
    size_t off = 0;
    u16* xb      = (u16*)(ws + off); off += (size_t)MROWS * 1024 * 2;          // 16.8 MB
    u16* Wall    = (u16*)(ws + off); off += (size_t)4352 * 1024 * 2;           // 8.9 MB (WcatT | WoT)
    u16* qkvg    = (u16*)(ws + off); off += (size_t)MROWS * QSTR * 2;          // 54.5 MB
    u16* MT_ws   = (u16*)(ws + off); off += (size_t)NBH * NCH * 2048 * 2;      // 8.4 MB (bf16)
    float* D_ws  = (float*)(ws + off); off += (size_t)NBH * NCH * 32 * 4;      // 0.26 MB
    u16* HT_ws   = (u16*)(ws + off); off += (size_t)NBH * NCH * 2048 * 2;      // 8.4 MB (bf16)
    u16* o_n     = (u16*)(ws + off); off += (size_t)MROWS * 1024 * 2;          // 16.8 MB
    u16* WcatT   = Wall;
    u16* WoT     = Wall + (size_t)3328 * 1024;

    prep_fused<<<8192 + 136 * 32, 256, 0, stream>>>(x, xb, Wq, Wk, Wv, Wg, Wgk1, Wo, Wall);
    gemm8<1><<<416, 512, 0, stream>>>(xb, WcatT, qkvg, MROWS, QSTR, 1024, 32);
    phaseA<<<NBH * NCH, 256, 0, stream>>>(qkvg, Wgk2, bgk2, MT_ws, D_ws);
    phaseB<<<128, 256, 0, stream>>>(MT_ws, D_ws, HT_ws);
    phaseC<<<NBH * NCH, 256, 0, stream>>>(qkvg, Wgk2, bgk2, HT_ws, gnw, o_n);
    gemm_sb<0><<<8 * 64, 256, 0, stream>>>(o_n, WoT, d_out, MROWS, 1024, 1024, 8);
}

// Round 15
// 173.528 us; speedup vs baseline: 1.0247x; 1.0247x over previous
//
#include <hip/hip_runtime.h>

typedef unsigned short u16;
typedef unsigned int u32;
typedef __attribute__((ext_vector_type(8))) short short8;
typedef __attribute__((ext_vector_type(4))) float f32x4;

#define KD 512
#define HEADS 16
#define DK 32
#define DV 64
#define TT 4096
#define MROWS 8192           // B*T
#define CHUNK 64
#define NCH 64               // T/CHUNK
#define NBH 32               // B*HEADS
#define QSTR 3328            // qkvg row stride (q 0 | k 512 | v 1024 | g 2048 | xg1 3072 | pad to 13*256)
#define SCALE 0.17677669529663687f  // 32^-0.5

__device__ __forceinline__ u16 f2bf(float f) {
    union { float f; unsigned int u; } x; x.f = f;
    unsigned int u = x.u;
    unsigned int r = (u + 0x7fffu + ((u >> 16) & 1u)) >> 16;
    return (u16)r;
}
__device__ __forceinline__ float bf2f(u16 s) {
    union { unsigned int u; float f; } x; x.u = ((unsigned int)s) << 16;
    return x.f;
}
__device__ __forceinline__ void gload16(const u16* g, u16* l) {
    __builtin_amdgcn_global_load_lds((const __attribute__((address_space(1))) u32*)g,
                                     (__attribute__((address_space(3))) u32*)l, 16, 0, 0);
}

// ---------------- fused prep: x cast + weight transposes ----------------
__global__ __launch_bounds__(256) void prep_fused(const float* __restrict__ x,
                                                  u16* __restrict__ xb,
                                                  const float* __restrict__ Wq,
                                                  const float* __restrict__ Wk,
                                                  const float* __restrict__ Wv,
                                                  const float* __restrict__ Wg,
                                                  const float* __restrict__ W1,
                                                  const float* __restrict__ Wo,
                                                  u16* __restrict__ dst) {
    __shared__ float tile[32][33];
    int bid = blockIdx.x;
    if (bid < 8192) {
        int i = bid * 256 + threadIdx.x;
        const float4 v = ((const float4*)x)[i];
        ushort4 o;
        o.x = f2bf(v.x); o.y = f2bf(v.y); o.z = f2bf(v.z); o.w = f2bf(v.w);
        ((ushort4*)xb)[i] = o;
        return;
    }
    int w = bid - 8192;
    int n0 = (w % 136) * 32, k0 = (w / 136) * 32;
    int tx = threadIdx.x & 31, ty = threadIdx.x >> 5;
    int n = n0 + tx;
    const float* src; int sN, cc;
    if (n < 512)       { src = Wq; sN = 512;  cc = n; }
    else if (n < 1024) { src = Wk; sN = 512;  cc = n - 512; }
    else if (n < 2048) { src = Wv; sN = 1024; cc = n - 1024; }
    else if (n < 3072) { src = Wg; sN = 1024; cc = n - 2048; }
    else if (n < 3088) { src = W1; sN = 16;   cc = n - 3072; }
    else if (n < 3328) { src = nullptr; sN = 0; cc = 0; }
    else               { src = Wo; sN = 1024; cc = n - 3328; }
    for (int r = ty; r < 32; r += 8)
        tile[r][tx] = src ? src[(size_t)(k0 + r) * sN + cc] : 0.f;
    __syncthreads();
    for (int r = ty; r < 32; r += 8)
        dst[(size_t)(n0 + r) * 1024 + k0 + tx] = f2bf(tile[tx][r]);
}

// ======================= 6-phase 256x256 GEMM (T2+T3+T4+T5) =======================
#define BARM() do { asm volatile("" ::: "memory"); __builtin_amdgcn_s_barrier(); asm volatile("" ::: "memory"); } while (0)
#define VMW(n) asm volatile("s_waitcnt vmcnt(" #n ")" ::: "memory")

template<int OUTBF>
__global__ __launch_bounds__(512, 2) void gemm8(const u16* __restrict__ A,
                                                const u16* __restrict__ Bt,
                                                void* __restrict__ C,
                                                int M, int N, int K, int nbx) {
    __shared__ u16 SA[2][16384];
    __shared__ u16 SB[2][16384];
    int nwg = gridDim.x, bid = blockIdx.x, cpx = nwg >> 3;
    int wg = (bid & 7) * cpx + (bid >> 3);       // XCD-chunked, bijective (nwg%8==0)
    int bx = wg % nbx, by = wg / nbx;            // by-major (R13-verified: FETCH 63.5 MB)
    int brow = by << 8, bcol = bx << 8;
    int tid = threadIdx.x;
    int wv = tid >> 6, lane = tid & 63;
    int wm = wv >> 2, wn = wv & 3;               // wave -> 128x64 C block
    int l15 = lane & 15, hi = lane >> 4;
    int rxor = l15 & 7;

    int srw = tid >> 3;
    int sg8 = ((tid & 7) ^ (srw & 7)) << 3;
    const u16* aBase = A + (size_t)(brow + srw) * K + sg8;
    const u16* bBase = Bt + (size_t)(bcol + ((tid >> 8) << 6) + (srw & 31)) * K + sg8;

#define STAGE_A(b, h, tt) do { \
        const u16* s_ = aBase + (size_t)(tt) * 64 + (size_t)(h) * 64 * K; \
        gload16(s_,                    &SA[b][(h) * 8192 + tid * 8]); \
        gload16(s_ + (size_t)128 * K,  &SA[b][(h) * 8192 + 4096 + tid * 8]); \
    } while (0)
#define STAGE_B(b, h, tt) do { \
        const u16* s_ = bBase + (size_t)(tt) * 64 + (size_t)(h) * 32 * K; \
        gload16(s_,                    &SB[b][(h) * 8192 + tid * 8]); \
        gload16(s_ + (size_t)128 * K,  &SB[b][(h) * 8192 + 4096 + tid * 8]); \
    } while (0)

    int aRow = (wm * 64 + l15) * 64;
    int bRow = (wn * 32 + l15) * 64;
    int cg0 = (hi ^ rxor) << 3;
    int cg1 = ((4 + hi) ^ rxor) << 3;

#define READ_A(dst, mh, b) do { \
        _Pragma("unroll") \
        for (int mil_ = 0; mil_ < 4; ++mil_) { \
            dst[mil_ * 2 + 0] = *(const short8*)&SA[b][(mh) * 8192 + mil_ * 1024 + aRow + cg0]; \
            dst[mil_ * 2 + 1] = *(const short8*)&SA[b][(mh) * 8192 + mil_ * 1024 + aRow + cg1]; \
        } } while (0)
#define READ_B(dst, nh, b) do { \
        _Pragma("unroll") \
        for (int nil_ = 0; nil_ < 2; ++nil_) { \
            dst[nil_ * 2 + 0] = *(const short8*)&SB[b][(nh) * 8192 + nil_ * 1024 + bRow + cg0]; \
            dst[nil_ * 2 + 1] = *(const short8*)&SB[b][(nh) * 8192 + nil_ * 1024 + bRow + cg1]; \
        } } while (0)

    f32x4 acc[8][4];
    #pragma unroll
    for (int mi = 0; mi < 8; ++mi)
        #pragma unroll
        for (int ni = 0; ni < 4; ++ni)
            acc[mi][ni] = (f32x4){0.f, 0.f, 0.f, 0.f};

#define MM(mb, nb, AF, BF) do { \
        __builtin_amdgcn_s_setprio(1); \
        _Pragma("unroll") \
        for (int ks_ = 0; ks_ < 2; ++ks_) \
        _Pragma("unroll") \
        for (int mil_ = 0; mil_ < 4; ++mil_) \
        _Pragma("unroll") \
        for (int nil_ = 0; nil_ < 2; ++nil_) \
            acc[(mb) + mil_][(nb) + nil_] = __builtin_amdgcn_mfma_f32_16x16x32_bf16( \
                AF[mil_ * 2 + ks_], BF[nil_ * 2 + ks_], acc[(mb) + mil_][(nb) + nil_], 0, 0, 0); \
        __builtin_amdgcn_s_setprio(0); \
    } while (0)

    int NK = K >> 6, NI = NK >> 1;
    STAGE_B(0, 0, 0); STAGE_A(0, 0, 0); STAGE_A(0, 1, 0); STAGE_B(0, 1, 0);
    STAGE_B(1, 0, 1); STAGE_A(1, 0, 1); STAGE_A(1, 1, 1);
    VMW(6);
    BARM();

    short8 alo[8], ahi[8], bb[4];
    for (int i = 0; i < NI; ++i) {
        int ta = 2 * i + 1; if (ta >= NK) ta = NK - 1;
        int tb = 2 * i + 2; if (tb >= NK) tb = NK - 1;
        int tc = 2 * i + 3; if (tc >= NK) tc = NK - 1;
        STAGE_B(1, 1, ta);
        READ_A(alo, 0, 0); READ_B(bb, 0, 0);
        BARM(); MM(0, 0, alo, bb); BARM();
        STAGE_B(0, 0, tb);
        READ_A(ahi, 1, 0);
        BARM(); MM(4, 0, ahi, bb); BARM();
        STAGE_A(0, 0, tb); STAGE_A(0, 1, tb);
        READ_B(bb, 1, 0);
        BARM(); MM(4, 2, ahi, bb); MM(0, 2, alo, bb);
        VMW(8);
        BARM();
        STAGE_B(0, 1, tb);
        READ_A(alo, 0, 1); READ_B(bb, 0, 1);
        BARM(); MM(0, 0, alo, bb); BARM();
        STAGE_B(1, 0, tc);
        READ_A(ahi, 1, 1);
        BARM(); MM(4, 0, ahi, bb);
        VMW(10);
        BARM();
        STAGE_A(1, 0, tc); STAGE_A(1, 1, tc);
        READ_B(bb, 1, 1);
        BARM(); MM(4, 2, ahi, bb); MM(0, 2, alo, bb);
        VMW(6);
        BARM();
    }

    // -------- epilogue: LDS-transposed vectorized store (reuse SA as per-wave slabs) --------
    VMW(0);            // drain the up-to-6 still-in-flight gload_lds targeting SA/SB
    BARM();            // all waves done reading LDS
    if (OUTBF) {
        u16* slab = &SA[0][0] + wv * (16 * 72);
        int r0 = brow + wm * 128;
        int c0 = bcol + wn * 64;
        int row = lane >> 2, colb = (lane & 3) * 8;
        #pragma unroll
        for (int mi = 0; mi < 8; ++mi) {
            #pragma unroll
            for (int ni = 0; ni < 4; ++ni)
                #pragma unroll
                for (int rr = 0; rr < 4; ++rr)
                    slab[(hi * 4 + rr) * 72 + ni * 16 + l15] = f2bf(acc[mi][ni][rr]);
            #pragma unroll
            for (int v = 0; v < 2; ++v) {
                short8 val = *(const short8*)&slab[row * 72 + colb + v * 32];
                *(short8*)((u16*)C + (size_t)(r0 + mi * 16 + row) * N + c0 + colb + v * 32) = val;
            }
        }
    } else {
        int r0 = brow + wm * 128 + (hi << 2);
        int c0 = bcol + wn * 64 + l15;
        #pragma unroll
        for (int mi = 0; mi < 8; ++mi)
            #pragma unroll
            for (int ni = 0; ni < 4; ++ni)
                #pragma unroll
                for (int rr = 0; rr < 4; ++rr)
                    ((float*)C)[(size_t)(r0 + mi * 16 + rr) * N + (c0 + ni * 16)] = acc[mi][ni][rr];
    }
#undef STAGE_A
#undef STAGE_B
#undef READ_A
#undef READ_B
#undef MM
}

// ---------------- 2-phase 128x128 GEMM (N=1024 out-proj: 512 blocks, 5/CU) ----------------
template<int OUTBF>
__global__ __launch_bounds__(256) void gemm_sb(const u16* __restrict__ A,
                                               const u16* __restrict__ Bt,
                                               void* __restrict__ C,
                                               int M, int N, int K, int nbx) {
    __shared__ u16 As[128 * 64];
    __shared__ u16 Bs[128 * 64];
    int nwg = gridDim.x;
    int bid = blockIdx.x;
    int cpx = nwg >> 3;
    int wg = (bid & 7) * cpx + (bid >> 3);
    int bx = wg % nbx, by = wg / nbx;
    int tid = threadIdx.x;
    int wave = tid >> 6, lane = tid & 63;
    int wr = wave >> 1, wc = wave & 1;
    int brow = by * 128, bcol = bx * 128;
    int srow = tid >> 3;
    int sgrp = (tid & 7) ^ (srow & 7);
    const u16* aS = A + (size_t)(brow + srow) * K + sgrp * 8;
    const u16* bS = Bt + (size_t)(bcol + srow) * K + sgrp * 8;
    f32x4 acc[4][4];
    #pragma unroll
    for (int mi = 0; mi < 4; ++mi)
        #pragma unroll
        for (int ni = 0; ni < 4; ++ni)
            acc[mi][ni] = (f32x4){0.f, 0.f, 0.f, 0.f};
    int l15 = lane & 15, hi = lane >> 4;
    int rxor = l15 & 7;
    for (int kt = 0; kt < K; kt += 64) {
        __syncthreads();
        #pragma unroll
        for (int i_ = 0; i_ < 4; ++i_) {
            gload16(aS + (size_t)i_ * 32 * K + kt, As + tid * 8 + i_ * 2048);
            gload16(bS + (size_t)i_ * 32 * K + kt, Bs + tid * 8 + i_ * 2048);
        }
        __syncthreads();
        #pragma unroll
        for (int ks = 0; ks < 2; ++ks) {
            short8 af[4], bfr[4];
            int g = ks * 4 + hi;
            #pragma unroll
            for (int i = 0; i < 4; ++i)
                af[i] = *(const short8*)(As + (size_t)(wr * 64 + i * 16 + l15) * 64 + ((g ^ rxor) << 3));
            #pragma unroll
            for (int i = 0; i < 4; ++i)
                bfr[i] = *(const short8*)(Bs + (size_t)(wc * 64 + i * 16 + l15) * 64 + ((g ^ rxor) << 3));
            #pragma unroll
            for (int mi = 0; mi < 4; ++mi)
                #pragma unroll
                for (int ni = 0; ni < 4; ++ni)
                    acc[mi][ni] = __builtin_amdgcn_mfma_f32_16x16x32_bf16(af[mi], bfr[ni], acc[mi][ni], 0, 0, 0);
        }
    }
    // -------- epilogue --------
    __syncthreads();
    if (!OUTBF) {
        float* slab = (float*)(wave < 2 ? (void*)As : (void*)Bs) + (wave & 1) * (16 * 68);
        int r0 = brow + wr * 64, c0 = bcol + wc * 64;
        int row = lane >> 2, colb = (lane & 3) * 4;
        #pragma unroll
        for (int mi = 0; mi < 4; ++mi) {
            #pragma unroll
            for (int ni = 0; ni < 4; ++ni)
                #pragma unroll
                for (int rr = 0; rr < 4; ++rr)
                    slab[(hi * 4 + rr) * 68 + ni * 16 + l15] = acc[mi][ni][rr];
            #pragma unroll
            for (int v = 0; v < 4; ++v) {
                float4 val = *(const float4*)&slab[row * 68 + colb + v * 16];
                *(float4*)((float*)C + (size_t)(r0 + mi * 16 + row) * N + c0 + colb + v * 16) = val;
            }
        }
    } else {
        u16* slab = As + wave * (16 * 72);
        int r0 = brow + wr * 64, c0 = bcol + wc * 64;
        int row = lane >> 2, colb = (lane & 3) * 8;
        #pragma unroll
        for (int mi = 0; mi < 4; ++mi) {
            #pragma unroll
            for (int ni = 0; ni < 4; ++ni)
                #pragma unroll
                for (int rr = 0; rr < 4; ++rr)
                    slab[(hi * 4 + rr) * 72 + ni * 16 + l15] = f2bf(acc[mi][ni][rr]);
            #pragma unroll
            for (int v = 0; v < 2; ++v) {
                short8 val = *(const short8*)&slab[row * 72 + colb + v * 32];
                *(short8*)((u16*)C + (size_t)(r0 + mi * 16 + row) * N + c0 + colb + v * 32) = val;
            }
        }
    }
}

// ---------------- gate slice: ls[j] = logsigmoid(xg1·W2[:,cc+j] + b2)/16, j=0..7 ----------------
__device__ __forceinline__ void gate_z8(const u16* __restrict__ xg,
                                        const float* __restrict__ W2,
                                        const float* __restrict__ b2,
                                        int cc, float* out8) {
    short8 x0 = *(const short8*)xg;
    short8 x1 = *(const short8*)(xg + 8);
    float z[8];
    float4 z0 = *(const float4*)(b2 + cc);
    float4 z1 = *(const float4*)(b2 + cc + 4);
    z[0]=z0.x; z[1]=z0.y; z[2]=z0.z; z[3]=z0.w;
    z[4]=z1.x; z[5]=z1.y; z[6]=z1.z; z[7]=z1.w;
    #pragma unroll
    for (int u = 0; u < 16; ++u) {
        float xu = bf2f((u16)(u < 8 ? x0[u] : x1[u - 8]));
        const float4 w0 = *(const float4*)(W2 + (size_t)u * 512 + cc);
        const float4 w1 = *(const float4*)(W2 + (size_t)u * 512 + cc + 4);
        z[0] += xu * w0.x; z[1] += xu * w0.y; z[2] += xu * w0.z; z[3] += xu * w0.w;
        z[4] += xu * w1.x; z[5] += xu * w1.y; z[6] += xu * w1.z; z[7] += xu * w1.w;
    }
    #pragma unroll
    for (int j = 0; j < 8; ++j) {
        float zz = z[j];
        out8[j] = (fminf(zz, 0.f) - log1pf(expf(-fabsf(zz)))) * 0.0625f;
    }
}

// ---------------- parallel inclusive cumsum over t (64 rows) of gkS[64][36] ----------------
__device__ __forceinline__ void scan64(float (*gkS)[36], float* Ztot, int tid) {
    int wv2 = tid >> 6, ln = tid & 63;
    #pragma unroll
    for (int ii = 0; ii < 8; ++ii) {
        int i = wv2 * 8 + ii;
        float v = gkS[ln][i];
        #pragma unroll
        for (int d = 1; d < 64; d <<= 1) {
            float u = __shfl_up(v, d);
            if (ln >= d) v += u;
        }
        gkS[ln][i] = v;
        if (Ztot && ln == 63) Ztot[i] = v;
    }
}

// ---------------- phase A (MFMA): gate+cumsum; M^T (bf16) via mfma -> MT, D ----------------
__global__ __launch_bounds__(256) void phaseA(const u16* __restrict__ qkvg,
                                              const float* __restrict__ W2,
                                              const float* __restrict__ b2,
                                              u16* __restrict__ MT_ws,
                                              float* __restrict__ D_ws) {
    int bh = blockIdx.x >> 6, c = blockIdx.x & 63;
    int b = bh >> 4, h = bh & 15;
    int t0 = b * TT + c * CHUNK;
    __shared__ float gkS[64][36];
    __shared__ u16 kdT_bf[32 * 72];
    __shared__ u16 VT_bf[64 * 72];
    __shared__ float Z[32];
    int tid = threadIdx.x;
    int s = tid >> 2, i0 = (tid & 3) << 3;
    {
        float ls[8];
        gate_z8(qkvg + (size_t)(t0 + s) * QSTR + 3072, W2, b2, h * DK + i0, ls);
        #pragma unroll
        for (int jj = 0; jj < 8; ++jj) gkS[s][i0 + jj] = ls[jj];
    }
    short8 kv = *(const short8*)(qkvg + (size_t)(t0 + s) * QSTR + 512 + h * DK + i0);
    {
        int j0 = (tid & 3) << 4;
        short8 v0 = *(const short8*)(qkvg + (size_t)(t0 + s) * QSTR + 1024 + h * DV + j0);
        short8 v1 = *(const short8*)(qkvg + (size_t)(t0 + s) * QSTR + 1024 + h * DV + j0 + 8);
        #pragma unroll
        for (int jj = 0; jj < 8; ++jj) {
            VT_bf[(j0 + jj) * 72 + s] = (u16)v0[jj];
            VT_bf[(j0 + 8 + jj) * 72 + s] = (u16)v1[jj];
        }
    }
    __syncthreads();
    scan64(gkS, Z, tid);
    __syncthreads();
    #pragma unroll
    for (int jj = 0; jj < 8; ++jj)
        kdT_bf[(i0 + jj) * 72 + s] = f2bf(expf(Z[i0 + jj] - gkS[s][i0 + jj]) * bf2f((u16)kv[jj]));
    __syncthreads();
    int wave = tid >> 6, lane = tid & 63, l15 = lane & 15, hi = lane >> 4;
    int it = wave & 1, jp = wave >> 1;
    size_t base = ((size_t)(bh * NCH + c)) * 2048;
    #pragma unroll
    for (int jj2 = 0; jj2 < 2; ++jj2) {
        int jt = jp * 2 + jj2;
        f32x4 mc = (f32x4){0.f, 0.f, 0.f, 0.f};
        #pragma unroll
        for (int kc = 0; kc < 2; ++kc) {
            short8 ak = *(const short8*)&kdT_bf[(it * 16 + l15) * 72 + kc * 32 + hi * 8];
            short8 bv = *(const short8*)&VT_bf[(jt * 16 + l15) * 72 + kc * 32 + hi * 8];
            mc = __builtin_amdgcn_mfma_f32_16x16x32_bf16(ak, bv, mc, 0, 0, 0);
        }
        #pragma unroll
        for (int rr = 0; rr < 4; ++rr)
            MT_ws[base + (size_t)(jt * 16 + l15) * 32 + it * 16 + hi * 4 + rr] = f2bf(mc[rr]);
    }
    if (tid < 32) D_ws[(size_t)(bh * NCH + c) * 32 + tid] = expf(Z[tid]);
}

// ---------------- phase B: chunk-state recurrence, 2 elems/thread, unrolled ----------------
__global__ __launch_bounds__(256) void phaseB(const u16* __restrict__ MT_ws,
                                              const float* __restrict__ D_ws,
                                              u16* __restrict__ HT_ws) {
    int idx = (blockIdx.x * 256 + threadIdx.x) * 2;
    int bh = idx >> 11;
    int ji = idx & 2047;
    int i = ji & 31;
    float h0 = 0.f, h1 = 0.f;
    size_t base = (size_t)bh * NCH * 2048 + ji;
    const float* dp = D_ws + (size_t)bh * NCH * 32 + i;
    #pragma unroll 4
    for (int c = 0; c < NCH; ++c) {
        u32 hp = ((u32)f2bf(h0)) | (((u32)f2bf(h1)) << 16);
        *(u32*)(HT_ws + base + (size_t)c * 2048) = hp;
        float d0 = dp[c * 32], d1 = dp[c * 32 + 1];
        u32 mp = *(const u32*)(MT_ws + base + (size_t)c * 2048);
        h0 = h0 * d0 + bf2f((u16)(mp & 0xffff));
        h1 = h1 * d1 + bf2f((u16)(mp >> 16));
    }
}

// ---------------- phase C (MFMA): score->mask->P, O = P@V + qh@H, fused RMS/swish ----------------
__global__ __launch_bounds__(256) void phaseC(const u16* __restrict__ qkvg,
                                              const float* __restrict__ W2,
                                              const float* __restrict__ b2,
                                              const u16* __restrict__ HT_ws,
                                              const float* __restrict__ gnw,
                                              u16* __restrict__ o_n) {
    int bh = blockIdx.x >> 6, c = blockIdx.x & 63;
    int b = bh >> 4, h = bh & 15;
    int t0 = b * TT + c * CHUNK;
    __shared__ float gkS[64][36];
    __shared__ u16 qh_bf[64 * 40];
    __shared__ u16 kt_bf[64 * 40];
    __shared__ u16 VT_bf[64 * 72];
    __shared__ u16 Ht_bf[64 * 40];
    u16* P_bf = (u16*)&gkS[0][0];
    int tid = threadIdx.x;
    int s = tid >> 2, i0 = (tid & 3) << 3;
    {
        float ls[8];
        gate_z8(qkvg + (size_t)(t0 + s) * QSTR + 3072, W2, b2, h * DK + i0, ls);
        #pragma unroll
        for (int jj = 0; jj < 8; ++jj) gkS[s][i0 + jj] = ls[jj];
    }
    short8 qv = *(const short8*)(qkvg + (size_t)(t0 + s) * QSTR + h * DK + i0);
    short8 kv = *(const short8*)(qkvg + (size_t)(t0 + s) * QSTR + 512 + h * DK + i0);
    {
        int j0 = (tid & 3) << 4;
        short8 v0 = *(const short8*)(qkvg + (size_t)(t0 + s) * QSTR + 1024 + h * DV + j0);
        short8 v1 = *(const short8*)(qkvg + (size_t)(t0 + s) * QSTR + 1024 + h * DV + j0 + 8);
        #pragma unroll
        for (int jj = 0; jj < 8; ++jj) {
            VT_bf[(j0 + jj) * 72 + s] = (u16)v0[jj];
            VT_bf[(j0 + 8 + jj) * 72 + s] = (u16)v1[jj];
        }
    }
    {
        const u16* hp = HT_ws + ((size_t)(bh * NCH + c)) * 2048 + tid * 8;
        short8 hv = *(const short8*)hp;
        int j = tid >> 2, ii0 = (tid & 3) << 3;
        *(short8*)&Ht_bf[j * 40 + ii0] = hv;
    }
    __syncthreads();
    scan64(gkS, nullptr, tid);
    __syncthreads();
    #pragma unroll
    for (int jj = 0; jj < 8; ++jj) {
        float Sv = gkS[s][i0 + jj];
        qh_bf[s * 40 + i0 + jj] = f2bf(bf2f((u16)qv[jj]) * expf(Sv) * SCALE);
        kt_bf[s * 40 + i0 + jj] = f2bf(bf2f((u16)kv[jj]) * expf(fminf(-Sv, 80.f)));
    }
    __syncthreads();
    int wave = tid >> 6, lane = tid & 63, l15 = lane & 15, hi = lane >> 4;
    int w = wave;
    short8 aq = *(const short8*)&qh_bf[(w * 16 + l15) * 40 + hi * 8];
    #pragma unroll
    for (int sn = 0; sn < 4; ++sn) {
        f32x4 sc = (f32x4){0.f, 0.f, 0.f, 0.f};
        if (sn <= w) {
            short8 bk = *(const short8*)&kt_bf[(sn * 16 + l15) * 40 + hi * 8];
            sc = __builtin_amdgcn_mfma_f32_16x16x32_bf16(aq, bk, sc, 0, 0, 0);
        }
        #pragma unroll
        for (int rr = 0; rr < 4; ++rr) {
            float val = sc[rr];
            if (sn > w || (sn == w && l15 > hi * 4 + rr)) val = 0.f;
            P_bf[(w * 16 + hi * 4 + rr) * 72 + sn * 16 + l15] = f2bf(val);
        }
    }
    __syncthreads();
    f32x4 acc[4];
    #pragma unroll
    for (int jn = 0; jn < 4; ++jn) {
        f32x4 a = (f32x4){0.f, 0.f, 0.f, 0.f};
        short8 bhf = *(const short8*)&Ht_bf[(jn * 16 + l15) * 40 + hi * 8];
        acc[jn] = __builtin_amdgcn_mfma_f32_16x16x32_bf16(aq, bhf, a, 0, 0, 0);
    }
    int nkc = (w < 2) ? 1 : 2;
    for (int kc = 0; kc < nkc; ++kc) {
        short8 ap = *(const short8*)&P_bf[(w * 16 + l15) * 72 + kc * 32 + hi * 8];
        #pragma unroll
        for (int jn = 0; jn < 4; ++jn) {
            short8 bv = *(const short8*)&VT_bf[(jn * 16 + l15) * 72 + kc * 32 + hi * 8];
            acc[jn] = __builtin_amdgcn_mfma_f32_16x16x32_bf16(ap, bv, acc[jn], 0, 0, 0);
        }
    }
    #pragma unroll
    for (int rr = 0; rr < 4; ++rr) {
        float sum2 = 0.f;
        #pragma unroll
        for (int jn = 0; jn < 4; ++jn) sum2 += acc[jn][rr] * acc[jn][rr];
        sum2 += __shfl_xor(sum2, 1);
        sum2 += __shfl_xor(sum2, 2);
        sum2 += __shfl_xor(sum2, 4);
        sum2 += __shfl_xor(sum2, 8);
        float rms = rsqrtf(sum2 * (1.f / 64.f) + 1e-5f);
        int t = w * 16 + hi * 4 + rr;
        #pragma unroll
        for (int jn = 0; jn < 4; ++jn) {
            int j = jn * 16 + l15;
            float g = bf2f(qkvg[(size_t)(t0 + t) * QSTR + 2048 + h * DV + j]);
            float sw = g / (1.f + expf(-g));
            float o = acc[jn][rr] * rms * gnw[j] * sw;
            o_n[(size_t)(t0 + t) * 1024 + h * DV + j] = f2bf(o);
        }
    }
}

// ---------------- launch ----------------
extern "C" void kernel_launch(void* const* d_in, const int* in_sizes, int n_in,
                              void* d_out, int out_size, void* d_ws, size_t ws_size,
                              hipStream_t stream) {
    const float* x    = (const float*)d_in[0];
    const float* Wq   = (const float*)d_in[1];
    const float* Wk   = (const float*)d_in[2];
    const float* Wv   = (const float*)d_in[3];
    const float* Wgk1 = (const float*)d_in[4];
    const float* Wgk2 = (const float*)d_in[5];
    const float* bgk2 = (const float*)d_in[6];
    const float* Wg   = (const float*)d_in[7];
    const float* gnw  = (const float*)d_in[8];
    const float* Wo   = (const float*)d_in[9];

    char* ws = (char*)d_ws;
    size_t off = 0;
    u16* xb      = (u16*)(ws + off); off += (size_t)MROWS * 1024 * 2;          // 16.8 MB
    u16* Wall    = (u16*)(ws + off); off += (size_t)4352 * 1024 * 2;           // 8.9 MB (WcatT | WoT)
    u16* qkvg    = (u16*)(ws + off); off += (size_t)MROWS * QSTR * 2;          // 54.5 MB
    u16* MT_ws   = (u16*)(ws + off); off += (size_t)NBH * NCH * 2048 * 2;      // 8.4 MB (bf16)
    float* D_ws  = (float*)(ws + off); off += (size_t)NBH * NCH * 32 * 4;      // 0.26 MB
    u16* HT_ws   = (u16*)(ws + off); off += (size_t)NBH * NCH * 2048 * 2;      // 8.4 MB (bf16)
    u16* o_n     = (u16*)(ws + off); off += (size_t)MROWS * 1024 * 2;          // 16.8 MB
    u16* WcatT   = Wall;
    u16* WoT     = Wall + (size_t)3328 * 1024;

    prep_fused<<<8192 + 136 * 32, 256, 0, stream>>>(x, xb, Wq, Wk, Wv, Wg, Wgk1, Wo, Wall);
    gemm8<1><<<416, 512, 0, stream>>>(xb, WcatT, qkvg, MROWS, QSTR, 1024, 13);
    phaseA<<<NBH * NCH, 256, 0, stream>>>(qkvg, Wgk2, bgk2, MT_ws, D_ws);
    phaseB<<<128, 256, 0, stream>>>(MT_ws, D_ws, HT_ws);
    phaseC<<<NBH * NCH, 256, 0, stream>>>(qkvg, Wgk2, bgk2, HT_ws, gnw, o_n);
    gemm_sb<0><<<8 * 64, 256, 0, stream>>>(o_n, WoT, d_out, MROWS, 1024, 1024, 8);
}

// Round 16
// 161.011 us; speedup vs baseline: 1.1043x; 1.0777x over previous
//
#include <hip/hip_runtime.h>

typedef unsigned short u16;
typedef unsigned int u32;
typedef __attribute__((ext_vector_type(8))) short short8;
typedef __attribute__((ext_vector_type(4))) float f32x4;

#define KD 512
#define HEADS 16
#define DK 32
#define DV 64
#define TT 4096
#define MROWS 8192           // B*T
#define CHUNK 64
#define NCH 64               // T/CHUNK
#define NBH 32               // B*HEADS
#define QSTR 3328            // qkvg row stride (q 0 | k 512 | v 1024 | g 2048 | xg1 3072 | pad to 13*256)
#define SCALE 0.17677669529663687f  // 32^-0.5

__device__ __forceinline__ u16 f2bf(float f) {
    union { float f; unsigned int u; } x; x.f = f;
    unsigned int u = x.u;
    unsigned int r = (u + 0x7fffu + ((u >> 16) & 1u)) >> 16;
    return (u16)r;
}
__device__ __forceinline__ float bf2f(u16 s) {
    union { unsigned int u; float f; } x; x.u = ((unsigned int)s) << 16;
    return x.f;
}
__device__ __forceinline__ void gload16(const u16* g, u16* l) {
    __builtin_amdgcn_global_load_lds((const __attribute__((address_space(1))) u32*)g,
                                     (__attribute__((address_space(3))) u32*)l, 16, 0, 0);
}

// ---------------- fused prep: x cast + weight transposes ----------------
__global__ __launch_bounds__(256) void prep_fused(const float* __restrict__ x,
                                                  u16* __restrict__ xb,
                                                  const float* __restrict__ Wq,
                                                  const float* __restrict__ Wk,
                                                  const float* __restrict__ Wv,
                                                  const float* __restrict__ Wg,
                                                  const float* __restrict__ W1,
                                                  const float* __restrict__ Wo,
                                                  u16* __restrict__ dst) {
    __shared__ float tile[32][33];
    int bid = blockIdx.x;
    if (bid < 8192) {
        int i = bid * 256 + threadIdx.x;
        const float4 v = ((const float4*)x)[i];
        ushort4 o;
        o.x = f2bf(v.x); o.y = f2bf(v.y); o.z = f2bf(v.z); o.w = f2bf(v.w);
        ((ushort4*)xb)[i] = o;
        return;
    }
    int w = bid - 8192;
    int n0 = (w % 136) * 32, k0 = (w / 136) * 32;
    int tx = threadIdx.x & 31, ty = threadIdx.x >> 5;
    int n = n0 + tx;
    const float* src; int sN, cc;
    if (n < 512)       { src = Wq; sN = 512;  cc = n; }
    else if (n < 1024) { src = Wk; sN = 512;  cc = n - 512; }
    else if (n < 2048) { src = Wv; sN = 1024; cc = n - 1024; }
    else if (n < 3072) { src = Wg; sN = 1024; cc = n - 2048; }
    else if (n < 3088) { src = W1; sN = 16;   cc = n - 3072; }
    else if (n < 3328) { src = nullptr; sN = 0; cc = 0; }
    else               { src = Wo; sN = 1024; cc = n - 3328; }
    for (int r = ty; r < 32; r += 8)
        tile[r][tx] = src ? src[(size_t)(k0 + r) * sN + cc] : 0.f;
    __syncthreads();
    for (int r = ty; r < 32; r += 8)
        dst[(size_t)(n0 + r) * 1024 + k0 + tx] = f2bf(tile[tx][r]);
}

// ======================= 6-phase 256x256 GEMM (T2+T3+T4+T5) =======================
#define BARM() do { asm volatile("" ::: "memory"); __builtin_amdgcn_s_barrier(); asm volatile("" ::: "memory"); } while (0)
#define VMW(n) asm volatile("s_waitcnt vmcnt(" #n ")" ::: "memory")

template<int OUTBF>
__global__ __launch_bounds__(512, 2) void gemm8(const u16* __restrict__ A,
                                                const u16* __restrict__ Bt,
                                                void* __restrict__ C,
                                                int M, int N, int K, int nbx) {
    __shared__ u16 SA[2][16384];
    __shared__ u16 SB[2][16384];
    int nwg = gridDim.x, bid = blockIdx.x, cpx = nwg >> 3;
    int wg = (bid & 7) * cpx + (bid >> 3);       // XCD-chunked, bijective (nwg%8==0)
    int bx = wg % nbx, by = wg / nbx;            // by-major (R13/R15-verified)
    int brow = by << 8, bcol = bx << 8;
    int tid = threadIdx.x;
    int wv = tid >> 6, lane = tid & 63;
    int wm = wv >> 2, wn = wv & 3;               // wave -> 128x64 C block
    int l15 = lane & 15, hi = lane >> 4;
    int rxor = l15 & 7;

    int srw = tid >> 3;
    int sg8 = ((tid & 7) ^ (srw & 7)) << 3;
    const u16* aBase = A + (size_t)(brow + srw) * K + sg8;
    const u16* bBase = Bt + (size_t)(bcol + ((tid >> 8) << 6) + (srw & 31)) * K + sg8;

#define STAGE_A(b, h, tt) do { \
        const u16* s_ = aBase + (size_t)(tt) * 64 + (size_t)(h) * 64 * K; \
        gload16(s_,                    &SA[b][(h) * 8192 + tid * 8]); \
        gload16(s_ + (size_t)128 * K,  &SA[b][(h) * 8192 + 4096 + tid * 8]); \
    } while (0)
#define STAGE_B(b, h, tt) do { \
        const u16* s_ = bBase + (size_t)(tt) * 64 + (size_t)(h) * 32 * K; \
        gload16(s_,                    &SB[b][(h) * 8192 + tid * 8]); \
        gload16(s_ + (size_t)128 * K,  &SB[b][(h) * 8192 + 4096 + tid * 8]); \
    } while (0)

    int aRow = (wm * 64 + l15) * 64;
    int bRow = (wn * 32 + l15) * 64;
    int cg0 = (hi ^ rxor) << 3;
    int cg1 = ((4 + hi) ^ rxor) << 3;

#define READ_A(dst, mh, b) do { \
        _Pragma("unroll") \
        for (int mil_ = 0; mil_ < 4; ++mil_) { \
            dst[mil_ * 2 + 0] = *(const short8*)&SA[b][(mh) * 8192 + mil_ * 1024 + aRow + cg0]; \
            dst[mil_ * 2 + 1] = *(const short8*)&SA[b][(mh) * 8192 + mil_ * 1024 + aRow + cg1]; \
        } } while (0)
#define READ_B(dst, nh, b) do { \
        _Pragma("unroll") \
        for (int nil_ = 0; nil_ < 2; ++nil_) { \
            dst[nil_ * 2 + 0] = *(const short8*)&SB[b][(nh) * 8192 + nil_ * 1024 + bRow + cg0]; \
            dst[nil_ * 2 + 1] = *(const short8*)&SB[b][(nh) * 8192 + nil_ * 1024 + bRow + cg1]; \
        } } while (0)

    f32x4 acc[8][4];
    #pragma unroll
    for (int mi = 0; mi < 8; ++mi)
        #pragma unroll
        for (int ni = 0; ni < 4; ++ni)
            acc[mi][ni] = (f32x4){0.f, 0.f, 0.f, 0.f};

#define MM(mb, nb, AF, BF) do { \
        __builtin_amdgcn_s_setprio(1); \
        _Pragma("unroll") \
        for (int ks_ = 0; ks_ < 2; ++ks_) \
        _Pragma("unroll") \
        for (int mil_ = 0; mil_ < 4; ++mil_) \
        _Pragma("unroll") \
        for (int nil_ = 0; nil_ < 2; ++nil_) \
            acc[(mb) + mil_][(nb) + nil_] = __builtin_amdgcn_mfma_f32_16x16x32_bf16( \
                AF[mil_ * 2 + ks_], BF[nil_ * 2 + ks_], acc[(mb) + mil_][(nb) + nil_], 0, 0, 0); \
        __builtin_amdgcn_s_setprio(0); \
    } while (0)

    int NK = K >> 6, NI = NK >> 1;
    STAGE_B(0, 0, 0); STAGE_A(0, 0, 0); STAGE_A(0, 1, 0); STAGE_B(0, 1, 0);
    STAGE_B(1, 0, 1); STAGE_A(1, 0, 1); STAGE_A(1, 1, 1);
    VMW(6);
    BARM();

    short8 alo[8], ahi[8], bb[4];
    for (int i = 0; i < NI; ++i) {
        int ta = 2 * i + 1; if (ta >= NK) ta = NK - 1;
        int tb = 2 * i + 2; if (tb >= NK) tb = NK - 1;
        int tc = 2 * i + 3; if (tc >= NK) tc = NK - 1;
        STAGE_B(1, 1, ta);
        READ_A(alo, 0, 0); READ_B(bb, 0, 0);
        BARM(); MM(0, 0, alo, bb); BARM();
        STAGE_B(0, 0, tb);
        READ_A(ahi, 1, 0);
        BARM(); MM(4, 0, ahi, bb); BARM();
        STAGE_A(0, 0, tb); STAGE_A(0, 1, tb);
        READ_B(bb, 1, 0);
        BARM(); MM(4, 2, ahi, bb); MM(0, 2, alo, bb);
        VMW(8);
        BARM();
        STAGE_B(0, 1, tb);
        READ_A(alo, 0, 1); READ_B(bb, 0, 1);
        BARM(); MM(0, 0, alo, bb); BARM();
        STAGE_B(1, 0, tc);
        READ_A(ahi, 1, 1);
        BARM(); MM(4, 0, ahi, bb);
        VMW(10);
        BARM();
        STAGE_A(1, 0, tc); STAGE_A(1, 1, tc);
        READ_B(bb, 1, 1);
        BARM(); MM(4, 2, ahi, bb); MM(0, 2, alo, bb);
        VMW(6);
        BARM();
    }

    // -------- epilogue: LDS-transposed vectorized store (reuse SA as per-wave slabs) --------
    VMW(0);
    BARM();
    if (OUTBF) {
        u16* slab = &SA[0][0] + wv * (16 * 72);
        int r0 = brow + wm * 128;
        int c0 = bcol + wn * 64;
        int row = lane >> 2, colb = (lane & 3) * 8;
        #pragma unroll
        for (int mi = 0; mi < 8; ++mi) {
            #pragma unroll
            for (int ni = 0; ni < 4; ++ni)
                #pragma unroll
                for (int rr = 0; rr < 4; ++rr)
                    slab[(hi * 4 + rr) * 72 + ni * 16 + l15] = f2bf(acc[mi][ni][rr]);
            #pragma unroll
            for (int v = 0; v < 2; ++v) {
                short8 val = *(const short8*)&slab[row * 72 + colb + v * 32];
                *(short8*)((u16*)C + (size_t)(r0 + mi * 16 + row) * N + c0 + colb + v * 32) = val;
            }
        }
    } else {
        int r0 = brow + wm * 128 + (hi << 2);
        int c0 = bcol + wn * 64 + l15;
        #pragma unroll
        for (int mi = 0; mi < 8; ++mi)
            #pragma unroll
            for (int ni = 0; ni < 4; ++ni)
                #pragma unroll
                for (int rr = 0; rr < 4; ++rr)
                    ((float*)C)[(size_t)(r0 + mi * 16 + rr) * N + (c0 + ni * 16)] = acc[mi][ni][rr];
    }
#undef STAGE_A
#undef STAGE_B
#undef READ_A
#undef READ_B
#undef MM
}

// ---------------- 2-phase 128x128 GEMM (N=1024 out-proj: 512 blocks, 5/CU) ----------------
template<int OUTBF>
__global__ __launch_bounds__(256) void gemm_sb(const u16* __restrict__ A,
                                               const u16* __restrict__ Bt,
                                               void* __restrict__ C,
                                               int M, int N, int K, int nbx) {
    __shared__ u16 As[128 * 64];
    __shared__ u16 Bs[128 * 64];
    int nwg = gridDim.x;
    int bid = blockIdx.x;
    int cpx = nwg >> 3;
    int wg = (bid & 7) * cpx + (bid >> 3);
    int bx = wg % nbx, by = wg / nbx;
    int tid = threadIdx.x;
    int wave = tid >> 6, lane = tid & 63;
    int wr = wave >> 1, wc = wave & 1;
    int brow = by * 128, bcol = bx * 128;
    int srow = tid >> 3;
    int sgrp = (tid & 7) ^ (srow & 7);
    const u16* aS = A + (size_t)(brow + srow) * K + sgrp * 8;
    const u16* bS = Bt + (size_t)(bcol + srow) * K + sgrp * 8;
    f32x4 acc[4][4];
    #pragma unroll
    for (int mi = 0; mi < 4; ++mi)
        #pragma unroll
        for (int ni = 0; ni < 4; ++ni)
            acc[mi][ni] = (f32x4){0.f, 0.f, 0.f, 0.f};
    int l15 = lane & 15, hi = lane >> 4;
    int rxor = l15 & 7;
    for (int kt = 0; kt < K; kt += 64) {
        __syncthreads();
        #pragma unroll
        for (int i_ = 0; i_ < 4; ++i_) {
            gload16(aS + (size_t)i_ * 32 * K + kt, As + tid * 8 + i_ * 2048);
            gload16(bS + (size_t)i_ * 32 * K + kt, Bs + tid * 8 + i_ * 2048);
        }
        __syncthreads();
        #pragma unroll
        for (int ks = 0; ks < 2; ++ks) {
            short8 af[4], bfr[4];
            int g = ks * 4 + hi;
            #pragma unroll
            for (int i = 0; i < 4; ++i)
                af[i] = *(const short8*)(As + (size_t)(wr * 64 + i * 16 + l15) * 64 + ((g ^ rxor) << 3));
            #pragma unroll
            for (int i = 0; i < 4; ++i)
                bfr[i] = *(const short8*)(Bs + (size_t)(wc * 64 + i * 16 + l15) * 64 + ((g ^ rxor) << 3));
            #pragma unroll
            for (int mi = 0; mi < 4; ++mi)
                #pragma unroll
                for (int ni = 0; ni < 4; ++ni)
                    acc[mi][ni] = __builtin_amdgcn_mfma_f32_16x16x32_bf16(af[mi], bfr[ni], acc[mi][ni], 0, 0, 0);
        }
    }
    // -------- epilogue --------
    __syncthreads();
    if (!OUTBF) {
        float* slab = (float*)(wave < 2 ? (void*)As : (void*)Bs) + (wave & 1) * (16 * 68);
        int r0 = brow + wr * 64, c0 = bcol + wc * 64;
        int row = lane >> 2, colb = (lane & 3) * 4;
        #pragma unroll
        for (int mi = 0; mi < 4; ++mi) {
            #pragma unroll
            for (int ni = 0; ni < 4; ++ni)
                #pragma unroll
                for (int rr = 0; rr < 4; ++rr)
                    slab[(hi * 4 + rr) * 68 + ni * 16 + l15] = acc[mi][ni][rr];
            #pragma unroll
            for (int v = 0; v < 4; ++v) {
                float4 val = *(const float4*)&slab[row * 68 + colb + v * 16];
                *(float4*)((float*)C + (size_t)(r0 + mi * 16 + row) * N + c0 + colb + v * 16) = val;
            }
        }
    } else {
        u16* slab = As + wave * (16 * 72);
        int r0 = brow + wr * 64, c0 = bcol + wc * 64;
        int row = lane >> 2, colb = (lane & 3) * 8;
        #pragma unroll
        for (int mi = 0; mi < 4; ++mi) {
            #pragma unroll
            for (int ni = 0; ni < 4; ++ni)
                #pragma unroll
                for (int rr = 0; rr < 4; ++rr)
                    slab[(hi * 4 + rr) * 72 + ni * 16 + l15] = f2bf(acc[mi][ni][rr]);
            #pragma unroll
            for (int v = 0; v < 2; ++v) {
                short8 val = *(const short8*)&slab[row * 72 + colb + v * 32];
                *(short8*)((u16*)C + (size_t)(r0 + mi * 16 + row) * N + c0 + colb + v * 32) = val;
            }
        }
    }
}

// ---------------- gate slice: ls[j] = logsigmoid(xg1·W2[:,cc+j] + b2)/16, j=0..7 ----------------
__device__ __forceinline__ void gate_z8(const u16* __restrict__ xg,
                                        const float* __restrict__ W2,
                                        const float* __restrict__ b2,
                                        int cc, float* out8) {
    short8 x0 = *(const short8*)xg;
    short8 x1 = *(const short8*)(xg + 8);
    float z[8];
    float4 z0 = *(const float4*)(b2 + cc);
    float4 z1 = *(const float4*)(b2 + cc + 4);
    z[0]=z0.x; z[1]=z0.y; z[2]=z0.z; z[3]=z0.w;
    z[4]=z1.x; z[5]=z1.y; z[6]=z1.z; z[7]=z1.w;
    #pragma unroll
    for (int u = 0; u < 16; ++u) {
        float xu = bf2f((u16)(u < 8 ? x0[u] : x1[u - 8]));
        const float4 w0 = *(const float4*)(W2 + (size_t)u * 512 + cc);
        const float4 w1 = *(const float4*)(W2 + (size_t)u * 512 + cc + 4);
        z[0] += xu * w0.x; z[1] += xu * w0.y; z[2] += xu * w0.z; z[3] += xu * w0.w;
        z[4] += xu * w1.x; z[5] += xu * w1.y; z[6] += xu * w1.z; z[7] += xu * w1.w;
    }
    #pragma unroll
    for (int j = 0; j < 8; ++j) {
        float zz = z[j];
        out8[j] = (fminf(zz, 0.f) - log1pf(expf(-fabsf(zz)))) * 0.0625f;
    }
}

// ---------------- parallel inclusive cumsum over t (64 rows) of gkS[64][36] ----------------
__device__ __forceinline__ void scan64(float (*gkS)[36], float* Ztot, int tid) {
    int wv2 = tid >> 6, ln = tid & 63;
    #pragma unroll
    for (int ii = 0; ii < 8; ++ii) {
        int i = wv2 * 8 + ii;
        float v = gkS[ln][i];
        #pragma unroll
        for (int d = 1; d < 64; d <<= 1) {
            float u = __shfl_up(v, d);
            if (ln >= d) v += u;
        }
        gkS[ln][i] = v;
        if (Ztot && ln == 63) Ztot[i] = v;
    }
}

// ---------------- phase A (MFMA): gate+cumsum -> S_ws; M^T (bf16) via mfma -> MT, D ----------------
__global__ __launch_bounds__(256) void phaseA(const u16* __restrict__ qkvg,
                                              const float* __restrict__ W2,
                                              const float* __restrict__ b2,
                                              float* __restrict__ S_ws,
                                              u16* __restrict__ MT_ws,
                                              float* __restrict__ D_ws) {
    int bh = blockIdx.x >> 6, c = blockIdx.x & 63;
    int b = bh >> 4, h = bh & 15;
    int t0 = b * TT + c * CHUNK;
    __shared__ float gkS[64][36];
    __shared__ u16 kdT_bf[32 * 72];
    __shared__ u16 VT_bf[64 * 72];
    __shared__ float Z[32];
    int tid = threadIdx.x;
    int s = tid >> 2, i0 = (tid & 3) << 3;
    {
        float ls[8];
        gate_z8(qkvg + (size_t)(t0 + s) * QSTR + 3072, W2, b2, h * DK + i0, ls);
        #pragma unroll
        for (int jj = 0; jj < 8; ++jj) gkS[s][i0 + jj] = ls[jj];
    }
    short8 kv = *(const short8*)(qkvg + (size_t)(t0 + s) * QSTR + 512 + h * DK + i0);
    {
        int j0 = (tid & 3) << 4;
        short8 v0 = *(const short8*)(qkvg + (size_t)(t0 + s) * QSTR + 1024 + h * DV + j0);
        short8 v1 = *(const short8*)(qkvg + (size_t)(t0 + s) * QSTR + 1024 + h * DV + j0 + 8);
        #pragma unroll
        for (int jj = 0; jj < 8; ++jj) {
            VT_bf[(j0 + jj) * 72 + s] = (u16)v0[jj];
            VT_bf[(j0 + 8 + jj) * 72 + s] = (u16)v1[jj];
        }
    }
    __syncthreads();
    scan64(gkS, Z, tid);
    __syncthreads();
    // store S (f32) for phaseC; compute kd
    {
        float* sp = S_ws + (size_t)(t0 + s) * KD + h * DK + i0;
        *(float4*)sp = *(const float4*)&gkS[s][i0];
        *(float4*)(sp + 4) = *(const float4*)&gkS[s][i0 + 4];
    }
    #pragma unroll
    for (int jj = 0; jj < 8; ++jj)
        kdT_bf[(i0 + jj) * 72 + s] = f2bf(expf(Z[i0 + jj] - gkS[s][i0 + jj]) * bf2f((u16)kv[jj]));
    __syncthreads();
    int wave = tid >> 6, lane = tid & 63, l15 = lane & 15, hi = lane >> 4;
    int it = wave & 1, jp = wave >> 1;
    size_t base = ((size_t)(bh * NCH + c)) * 2048;
    #pragma unroll
    for (int jj2 = 0; jj2 < 2; ++jj2) {
        int jt = jp * 2 + jj2;
        f32x4 mc = (f32x4){0.f, 0.f, 0.f, 0.f};
        #pragma unroll
        for (int kc = 0; kc < 2; ++kc) {
            short8 ak = *(const short8*)&kdT_bf[(it * 16 + l15) * 72 + kc * 32 + hi * 8];
            short8 bv = *(const short8*)&VT_bf[(jt * 16 + l15) * 72 + kc * 32 + hi * 8];
            mc = __builtin_amdgcn_mfma_f32_16x16x32_bf16(ak, bv, mc, 0, 0, 0);
        }
        #pragma unroll
        for (int rr = 0; rr < 4; ++rr)
            MT_ws[base + (size_t)(jt * 16 + l15) * 32 + it * 16 + hi * 4 + rr] = f2bf(mc[rr]);
    }
    if (tid < 32) D_ws[(size_t)(bh * NCH + c) * 32 + tid] = expf(Z[tid]);
}

// ---------------- phase B: chunk-state recurrence, 2 elems/thread, unrolled ----------------
__global__ __launch_bounds__(256) void phaseB(const u16* __restrict__ MT_ws,
                                              const float* __restrict__ D_ws,
                                              u16* __restrict__ HT_ws) {
    int idx = (blockIdx.x * 256 + threadIdx.x) * 2;
    int bh = idx >> 11;
    int ji = idx & 2047;
    int i = ji & 31;
    float h0 = 0.f, h1 = 0.f;
    size_t base = (size_t)bh * NCH * 2048 + ji;
    const float* dp = D_ws + (size_t)bh * NCH * 32 + i;
    #pragma unroll 4
    for (int c = 0; c < NCH; ++c) {
        u32 hp = ((u32)f2bf(h0)) | (((u32)f2bf(h1)) << 16);
        *(u32*)(HT_ws + base + (size_t)c * 2048) = hp;
        float d0 = dp[c * 32], d1 = dp[c * 32 + 1];
        u32 mp = *(const u32*)(MT_ws + base + (size_t)c * 2048);
        h0 = h0 * d0 + bf2f((u16)(mp & 0xffff));
        h1 = h1 * d1 + bf2f((u16)(mp >> 16));
    }
}

// ---------------- phase C (MFMA): load S; score->mask->P, O = P@V + qh@H, RMS/swish ----------------
__global__ __launch_bounds__(256) void phaseC(const u16* __restrict__ qkvg,
                                              const float* __restrict__ S_ws,
                                              const u16* __restrict__ HT_ws,
                                              const float* __restrict__ gnw,
                                              u16* __restrict__ o_n) {
    int bh = blockIdx.x >> 6, c = blockIdx.x & 63;
    int b = bh >> 4, h = bh & 15;
    int t0 = b * TT + c * CHUNK;
    __shared__ u16 P_bf[64 * 72];
    __shared__ u16 qh_bf[64 * 40];
    __shared__ u16 kt_bf[64 * 40];
    __shared__ u16 VT_bf[64 * 72];
    __shared__ u16 Ht_bf[64 * 40];
    int tid = threadIdx.x;
    int s = tid >> 2, i0 = (tid & 3) << 3;
    short8 qv = *(const short8*)(qkvg + (size_t)(t0 + s) * QSTR + h * DK + i0);
    short8 kv = *(const short8*)(qkvg + (size_t)(t0 + s) * QSTR + 512 + h * DK + i0);
    // S from phaseA (bit-identical to recomputation)
    float Sv[8];
    {
        const float* sp = S_ws + (size_t)(t0 + s) * KD + h * DK + i0;
        float4 S0 = *(const float4*)sp, S1 = *(const float4*)(sp + 4);
        Sv[0]=S0.x; Sv[1]=S0.y; Sv[2]=S0.z; Sv[3]=S0.w;
        Sv[4]=S1.x; Sv[5]=S1.y; Sv[6]=S1.z; Sv[7]=S1.w;
    }
    {
        int j0 = (tid & 3) << 4;
        short8 v0 = *(const short8*)(qkvg + (size_t)(t0 + s) * QSTR + 1024 + h * DV + j0);
        short8 v1 = *(const short8*)(qkvg + (size_t)(t0 + s) * QSTR + 1024 + h * DV + j0 + 8);
        #pragma unroll
        for (int jj = 0; jj < 8; ++jj) {
            VT_bf[(j0 + jj) * 72 + s] = (u16)v0[jj];
            VT_bf[(j0 + 8 + jj) * 72 + s] = (u16)v1[jj];
        }
    }
    {
        const u16* hp = HT_ws + ((size_t)(bh * NCH + c)) * 2048 + tid * 8;
        short8 hv = *(const short8*)hp;
        int j = tid >> 2, ii0 = (tid & 3) << 3;
        *(short8*)&Ht_bf[j * 40 + ii0] = hv;
    }
    #pragma unroll
    for (int jj = 0; jj < 8; ++jj) {
        qh_bf[s * 40 + i0 + jj] = f2bf(bf2f((u16)qv[jj]) * expf(Sv[jj]) * SCALE);
        kt_bf[s * 40 + i0 + jj] = f2bf(bf2f((u16)kv[jj]) * expf(fminf(-Sv[jj], 80.f)));
    }
    __syncthreads();
    int wave = tid >> 6, lane = tid & 63, l15 = lane & 15, hi = lane >> 4;
    int w = wave;
    short8 aq = *(const short8*)&qh_bf[(w * 16 + l15) * 40 + hi * 8];
    #pragma unroll
    for (int sn = 0; sn < 4; ++sn) {
        f32x4 sc = (f32x4){0.f, 0.f, 0.f, 0.f};
        if (sn <= w) {
            short8 bk = *(const short8*)&kt_bf[(sn * 16 + l15) * 40 + hi * 8];
            sc = __builtin_amdgcn_mfma_f32_16x16x32_bf16(aq, bk, sc, 0, 0, 0);
        }
        #pragma unroll
        for (int rr = 0; rr < 4; ++rr) {
            float val = sc[rr];
            if (sn > w || (sn == w && l15 > hi * 4 + rr)) val = 0.f;
            P_bf[(w * 16 + hi * 4 + rr) * 72 + sn * 16 + l15] = f2bf(val);
        }
    }
    __syncthreads();
    f32x4 acc[4];
    #pragma unroll
    for (int jn = 0; jn < 4; ++jn) {
        f32x4 a = (f32x4){0.f, 0.f, 0.f, 0.f};
        short8 bhf = *(const short8*)&Ht_bf[(jn * 16 + l15) * 40 + hi * 8];
        acc[jn] = __builtin_amdgcn_mfma_f32_16x16x32_bf16(aq, bhf, a, 0, 0, 0);
    }
    int nkc = (w < 2) ? 1 : 2;
    for (int kc = 0; kc < nkc; ++kc) {
        short8 ap = *(const short8*)&P_bf[(w * 16 + l15) * 72 + kc * 32 + hi * 8];
        #pragma unroll
        for (int jn = 0; jn < 4; ++jn) {
            short8 bv = *(const short8*)&VT_bf[(jn * 16 + l15) * 72 + kc * 32 + hi * 8];
            acc[jn] = __builtin_amdgcn_mfma_f32_16x16x32_bf16(ap, bv, acc[jn], 0, 0, 0);
        }
    }
    #pragma unroll
    for (int rr = 0; rr < 4; ++rr) {
        float sum2 = 0.f;
        #pragma unroll
        for (int jn = 0; jn < 4; ++jn) sum2 += acc[jn][rr] * acc[jn][rr];
        sum2 += __shfl_xor(sum2, 1);
        sum2 += __shfl_xor(sum2, 2);
        sum2 += __shfl_xor(sum2, 4);
        sum2 += __shfl_xor(sum2, 8);
        float rms = rsqrtf(sum2 * (1.f / 64.f) + 1e-5f);
        int t = w * 16 + hi * 4 + rr;
        #pragma unroll
        for (int jn = 0; jn < 4; ++jn) {
            int j = jn * 16 + l15;
            float g = bf2f(qkvg[(size_t)(t0 + t) * QSTR + 2048 + h * DV + j]);
            float sw = g / (1.f + expf(-g));
            float o = acc[jn][rr] * rms * gnw[j] * sw;
            o_n[(size_t)(t0 + t) * 1024 + h * DV + j] = f2bf(o);
        }
    }
}

// ---------------- launch ----------------
extern "C" void kernel_launch(void* const* d_in, const int* in_sizes, int n_in,
                              void* d_out, int out_size, void* d_ws, size_t ws_size,
                              hipStream_t stream) {
    const float* x    = (const float*)d_in[0];
    const float* Wq   = (const float*)d_in[1];
    const float* Wk   = (const float*)d_in[2];
    const float* Wv   = (const float*)d_in[3];
    const float* Wgk1 = (const float*)d_in[4];
    const float* Wgk2 = (const float*)d_in[5];
    const float* bgk2 = (const float*)d_in[6];
    const float* Wg   = (const float*)d_in[7];
    const float* gnw  = (const float*)d_in[8];
    const float* Wo   = (const float*)d_in[9];

    char* ws = (char*)d_ws;
    size_t off = 0;
    u16* xb      = (u16*)(ws + off); off += (size_t)MROWS * 1024 * 2;          // 16.8 MB
    u16* Wall    = (u16*)(ws + off); off += (size_t)4352 * 1024 * 2;           // 8.9 MB (WcatT | WoT)
    u16* qkvg    = (u16*)(ws + off); off += (size_t)MROWS * QSTR * 2;          // 54.5 MB
    float* S_ws  = (float*)(ws + off); off += (size_t)MROWS * KD * 4;          // 16.8 MB
    u16* MT_ws   = (u16*)(ws + off); off += (size_t)NBH * NCH * 2048 * 2;      // 8.4 MB (bf16)
    float* D_ws  = (float*)(ws + off); off += (size_t)NBH * NCH * 32 * 4;      // 0.26 MB
    u16* HT_ws   = (u16*)(ws + off); off += (size_t)NBH * NCH * 2048 * 2;      // 8.4 MB (bf16)
    u16* o_n     = (u16*)(ws + off); off += (size_t)MROWS * 1024 * 2;          // 16.8 MB
    u16* WcatT   = Wall;
    u16* WoT     = Wall + (size_t)3328 * 1024;

    prep_fused<<<8192 + 136 * 32, 256, 0, stream>>>(x, xb, Wq, Wk, Wv, Wg, Wgk1, Wo, Wall);
    gemm8<1><<<416, 512, 0, stream>>>(xb, WcatT, qkvg, MROWS, QSTR, 1024, 13);
    phaseA<<<NBH * NCH, 256, 0, stream>>>(qkvg, Wgk2, bgk2, S_ws, MT_ws, D_ws);
    phaseB<<<128, 256, 0, stream>>>(MT_ws, D_ws, HT_ws);
    phaseC<<<NBH * NCH, 256, 0, stream>>>(qkvg, S_ws, HT_ws, gnw, o_n);
    gemm_sb<0><<<8 * 64, 256, 0, stream>>>(o_n, WoT, d_out, MROWS, 1024, 1024, 8);
}

// Round 17
// 158.785 us; speedup vs baseline: 1.1198x; 1.0140x over previous
//
#include <hip/hip_runtime.h>

typedef unsigned short u16;
typedef unsigned int u32;
typedef __attribute__((ext_vector_type(8))) short short8;
typedef __attribute__((ext_vector_type(4))) float f32x4;

#define KD 512
#define HEADS 16
#define DK 32
#define DV 64
#define TT 4096
#define MROWS 8192           // B*T
#define CHUNK 64
#define NCH 64               // T/CHUNK
#define NBH 32               // B*HEADS
#define QSTR 3328            // qkvg row stride (q 0 | k 512 | v 1024 | g 2048 | xg1 3072 | pad to 13*256)
#define SCALE 0.17677669529663687f  // 32^-0.5

__device__ __forceinline__ u16 f2bf(float f) {
    union { float f; unsigned int u; } x; x.f = f;
    unsigned int u = x.u;
    unsigned int r = (u + 0x7fffu + ((u >> 16) & 1u)) >> 16;
    return (u16)r;
}
__device__ __forceinline__ float bf2f(u16 s) {
    union { unsigned int u; float f; } x; x.u = ((unsigned int)s) << 16;
    return x.f;
}
__device__ __forceinline__ void gload16(const u16* g, u16* l) {
    __builtin_amdgcn_global_load_lds((const __attribute__((address_space(1))) u32*)g,
                                     (__attribute__((address_space(3))) u32*)l, 16, 0, 0);
}

// ---------------- fused prep: x cast + weight transposes ----------------
__global__ __launch_bounds__(256) void prep_fused(const float* __restrict__ x,
                                                  u16* __restrict__ xb,
                                                  const float* __restrict__ Wq,
                                                  const float* __restrict__ Wk,
                                                  const float* __restrict__ Wv,
                                                  const float* __restrict__ Wg,
                                                  const float* __restrict__ W1,
                                                  const float* __restrict__ Wo,
                                                  u16* __restrict__ dst) {
    __shared__ float tile[32][33];
    int bid = blockIdx.x;
    if (bid < 8192) {
        int i = bid * 256 + threadIdx.x;
        const float4 v = ((const float4*)x)[i];
        ushort4 o;
        o.x = f2bf(v.x); o.y = f2bf(v.y); o.z = f2bf(v.z); o.w = f2bf(v.w);
        ((ushort4*)xb)[i] = o;
        return;
    }
    int w = bid - 8192;
    int n0 = (w % 136) * 32, k0 = (w / 136) * 32;
    int tx = threadIdx.x & 31, ty = threadIdx.x >> 5;
    int n = n0 + tx;
    const float* src; int sN, cc;
    if (n < 512)       { src = Wq; sN = 512;  cc = n; }
    else if (n < 1024) { src = Wk; sN = 512;  cc = n - 512; }
    else if (n < 2048) { src = Wv; sN = 1024; cc = n - 1024; }
    else if (n < 3072) { src = Wg; sN = 1024; cc = n - 2048; }
    else if (n < 3088) { src = W1; sN = 16;   cc = n - 3072; }
    else if (n < 3328) { src = nullptr; sN = 0; cc = 0; }
    else               { src = Wo; sN = 1024; cc = n - 3328; }
    for (int r = ty; r < 32; r += 8)
        tile[r][tx] = src ? src[(size_t)(k0 + r) * sN + cc] : 0.f;
    __syncthreads();
    for (int r = ty; r < 32; r += 8)
        dst[(size_t)(n0 + r) * 1024 + k0 + tx] = f2bf(tile[tx][r]);
}

// ======================= 6-phase 256x256 GEMM (T2+T3+T4+T5) =======================
#define BARM() do { asm volatile("" ::: "memory"); __builtin_amdgcn_s_barrier(); asm volatile("" ::: "memory"); } while (0)
#define VMW(n) asm volatile("s_waitcnt vmcnt(" #n ")" ::: "memory")

template<int OUTBF>
__global__ __launch_bounds__(512, 2) void gemm8(const u16* __restrict__ A,
                                                const u16* __restrict__ Bt,
                                                void* __restrict__ C,
                                                int M, int N, int K, int nbx) {
    __shared__ u16 SA[2][16384];
    __shared__ u16 SB[2][16384];
    int nwg = gridDim.x, bid = blockIdx.x, cpx = nwg >> 3;
    int wg = (bid & 7) * cpx + (bid >> 3);       // XCD-chunked, bijective (nwg%8==0)
    int bx = wg % nbx, by = wg / nbx;            // by-major (R13/R15-verified)
    int brow = by << 8, bcol = bx << 8;
    int tid = threadIdx.x;
    int wv = tid >> 6, lane = tid & 63;
    int wm = wv >> 2, wn = wv & 3;
    int l15 = lane & 15, hi = lane >> 4;
    int rxor = l15 & 7;

    int srw = tid >> 3;
    int sg8 = ((tid & 7) ^ (srw & 7)) << 3;
    const u16* aBase = A + (size_t)(brow + srw) * K + sg8;
    const u16* bBase = Bt + (size_t)(bcol + ((tid >> 8) << 6) + (srw & 31)) * K + sg8;

#define STAGE_A(b, h, tt) do { \
        const u16* s_ = aBase + (size_t)(tt) * 64 + (size_t)(h) * 64 * K; \
        gload16(s_,                    &SA[b][(h) * 8192 + tid * 8]); \
        gload16(s_ + (size_t)128 * K,  &SA[b][(h) * 8192 + 4096 + tid * 8]); \
    } while (0)
#define STAGE_B(b, h, tt) do { \
        const u16* s_ = bBase + (size_t)(tt) * 64 + (size_t)(h) * 32 * K; \
        gload16(s_,                    &SB[b][(h) * 8192 + tid * 8]); \
        gload16(s_ + (size_t)128 * K,  &SB[b][(h) * 8192 + 4096 + tid * 8]); \
    } while (0)

    int aRow = (wm * 64 + l15) * 64;
    int bRow = (wn * 32 + l15) * 64;
    int cg0 = (hi ^ rxor) << 3;
    int cg1 = ((4 + hi) ^ rxor) << 3;

#define READ_A(dst, mh, b) do { \
        _Pragma("unroll") \
        for (int mil_ = 0; mil_ < 4; ++mil_) { \
            dst[mil_ * 2 + 0] = *(const short8*)&SA[b][(mh) * 8192 + mil_ * 1024 + aRow + cg0]; \
            dst[mil_ * 2 + 1] = *(const short8*)&SA[b][(mh) * 8192 + mil_ * 1024 + aRow + cg1]; \
        } } while (0)
#define READ_B(dst, nh, b) do { \
        _Pragma("unroll") \
        for (int nil_ = 0; nil_ < 2; ++nil_) { \
            dst[nil_ * 2 + 0] = *(const short8*)&SB[b][(nh) * 8192 + nil_ * 1024 + bRow + cg0]; \
            dst[nil_ * 2 + 1] = *(const short8*)&SB[b][(nh) * 8192 + nil_ * 1024 + bRow + cg1]; \
        } } while (0)

    f32x4 acc[8][4];
    #pragma unroll
    for (int mi = 0; mi < 8; ++mi)
        #pragma unroll
        for (int ni = 0; ni < 4; ++ni)
            acc[mi][ni] = (f32x4){0.f, 0.f, 0.f, 0.f};

#define MM(mb, nb, AF, BF) do { \
        __builtin_amdgcn_s_setprio(1); \
        _Pragma("unroll") \
        for (int ks_ = 0; ks_ < 2; ++ks_) \
        _Pragma("unroll") \
        for (int mil_ = 0; mil_ < 4; ++mil_) \
        _Pragma("unroll") \
        for (int nil_ = 0; nil_ < 2; ++nil_) \
            acc[(mb) + mil_][(nb) + nil_] = __builtin_amdgcn_mfma_f32_16x16x32_bf16( \
                AF[mil_ * 2 + ks_], BF[nil_ * 2 + ks_], acc[(mb) + mil_][(nb) + nil_], 0, 0, 0); \
        __builtin_amdgcn_s_setprio(0); \
    } while (0)

    int NK = K >> 6, NI = NK >> 1;
    STAGE_B(0, 0, 0); STAGE_A(0, 0, 0); STAGE_A(0, 1, 0); STAGE_B(0, 1, 0);
    STAGE_B(1, 0, 1); STAGE_A(1, 0, 1); STAGE_A(1, 1, 1);
    VMW(6);
    BARM();

    short8 alo[8], ahi[8], bb[4];
    for (int i = 0; i < NI; ++i) {
        int ta = 2 * i + 1; if (ta >= NK) ta = NK - 1;
        int tb = 2 * i + 2; if (tb >= NK) tb = NK - 1;
        int tc = 2 * i + 3; if (tc >= NK) tc = NK - 1;
        STAGE_B(1, 1, ta);
        READ_A(alo, 0, 0); READ_B(bb, 0, 0);
        BARM(); MM(0, 0, alo, bb); BARM();
        STAGE_B(0, 0, tb);
        READ_A(ahi, 1, 0);
        BARM(); MM(4, 0, ahi, bb); BARM();
        STAGE_A(0, 0, tb); STAGE_A(0, 1, tb);
        READ_B(bb, 1, 0);
        BARM(); MM(4, 2, ahi, bb); MM(0, 2, alo, bb);
        VMW(8);
        BARM();
        STAGE_B(0, 1, tb);
        READ_A(alo, 0, 1); READ_B(bb, 0, 1);
        BARM(); MM(0, 0, alo, bb); BARM();
        STAGE_B(1, 0, tc);
        READ_A(ahi, 1, 1);
        BARM(); MM(4, 0, ahi, bb);
        VMW(10);
        BARM();
        STAGE_A(1, 0, tc); STAGE_A(1, 1, tc);
        READ_B(bb, 1, 1);
        BARM(); MM(4, 2, ahi, bb); MM(0, 2, alo, bb);
        VMW(6);
        BARM();
    }

    VMW(0);
    BARM();
    if (OUTBF) {
        u16* slab = &SA[0][0] + wv * (16 * 72);
        int r0 = brow + wm * 128;
        int c0 = bcol + wn * 64;
        int row = lane >> 2, colb = (lane & 3) * 8;
        #pragma unroll
        for (int mi = 0; mi < 8; ++mi) {
            #pragma unroll
            for (int ni = 0; ni < 4; ++ni)
                #pragma unroll
                for (int rr = 0; rr < 4; ++rr)
                    slab[(hi * 4 + rr) * 72 + ni * 16 + l15] = f2bf(acc[mi][ni][rr]);
            #pragma unroll
            for (int v = 0; v < 2; ++v) {
                short8 val = *(const short8*)&slab[row * 72 + colb + v * 32];
                *(short8*)((u16*)C + (size_t)(r0 + mi * 16 + row) * N + c0 + colb + v * 32) = val;
            }
        }
    } else {
        int r0 = brow + wm * 128 + (hi << 2);
        int c0 = bcol + wn * 64 + l15;
        #pragma unroll
        for (int mi = 0; mi < 8; ++mi)
            #pragma unroll
            for (int ni = 0; ni < 4; ++ni)
                #pragma unroll
                for (int rr = 0; rr < 4; ++rr)
                    ((float*)C)[(size_t)(r0 + mi * 16 + rr) * N + (c0 + ni * 16)] = acc[mi][ni][rr];
    }
#undef STAGE_A
#undef STAGE_B
#undef READ_A
#undef READ_B
#undef MM
}

// ---------------- 2-phase 128x128 GEMM (N=1024 out-proj: 512 blocks, 5/CU) ----------------
template<int OUTBF>
__global__ __launch_bounds__(256) void gemm_sb(const u16* __restrict__ A,
                                               const u16* __restrict__ Bt,
                                               void* __restrict__ C,
                                               int M, int N, int K, int nbx) {
    __shared__ u16 As[128 * 64];
    __shared__ u16 Bs[128 * 64];
    int nwg = gridDim.x;
    int bid = blockIdx.x;
    int cpx = nwg >> 3;
    int wg = (bid & 7) * cpx + (bid >> 3);
    int bx = wg % nbx, by = wg / nbx;
    int tid = threadIdx.x;
    int wave = tid >> 6, lane = tid & 63;
    int wr = wave >> 1, wc = wave & 1;
    int brow = by * 128, bcol = bx * 128;
    int srow = tid >> 3;
    int sgrp = (tid & 7) ^ (srow & 7);
    const u16* aS = A + (size_t)(brow + srow) * K + sgrp * 8;
    const u16* bS = Bt + (size_t)(bcol + srow) * K + sgrp * 8;
    f32x4 acc[4][4];
    #pragma unroll
    for (int mi = 0; mi < 4; ++mi)
        #pragma unroll
        for (int ni = 0; ni < 4; ++ni)
            acc[mi][ni] = (f32x4){0.f, 0.f, 0.f, 0.f};
    int l15 = lane & 15, hi = lane >> 4;
    int rxor = l15 & 7;
    for (int kt = 0; kt < K; kt += 64) {
        __syncthreads();
        #pragma unroll
        for (int i_ = 0; i_ < 4; ++i_) {
            gload16(aS + (size_t)i_ * 32 * K + kt, As + tid * 8 + i_ * 2048);
            gload16(bS + (size_t)i_ * 32 * K + kt, Bs + tid * 8 + i_ * 2048);
        }
        __syncthreads();
        #pragma unroll
        for (int ks = 0; ks < 2; ++ks) {
            short8 af[4], bfr[4];
            int g = ks * 4 + hi;
            #pragma unroll
            for (int i = 0; i < 4; ++i)
                af[i] = *(const short8*)(As + (size_t)(wr * 64 + i * 16 + l15) * 64 + ((g ^ rxor) << 3));
            #pragma unroll
            for (int i = 0; i < 4; ++i)
                bfr[i] = *(const short8*)(Bs + (size_t)(wc * 64 + i * 16 + l15) * 64 + ((g ^ rxor) << 3));
            #pragma unroll
            for (int mi = 0; mi < 4; ++mi)
                #pragma unroll
                for (int ni = 0; ni < 4; ++ni)
                    acc[mi][ni] = __builtin_amdgcn_mfma_f32_16x16x32_bf16(af[mi], bfr[ni], acc[mi][ni], 0, 0, 0);
        }
    }
    __syncthreads();
    if (!OUTBF) {
        float* slab = (float*)(wave < 2 ? (void*)As : (void*)Bs) + (wave & 1) * (16 * 68);
        int r0 = brow + wr * 64, c0 = bcol + wc * 64;
        int row = lane >> 2, colb = (lane & 3) * 4;
        #pragma unroll
        for (int mi = 0; mi < 4; ++mi) {
            #pragma unroll
            for (int ni = 0; ni < 4; ++ni)
                #pragma unroll
                for (int rr = 0; rr < 4; ++rr)
                    slab[(hi * 4 + rr) * 68 + ni * 16 + l15] = acc[mi][ni][rr];
            #pragma unroll
            for (int v = 0; v < 4; ++v) {
                float4 val = *(const float4*)&slab[row * 68 + colb + v * 16];
                *(float4*)((float*)C + (size_t)(r0 + mi * 16 + row) * N + c0 + colb + v * 16) = val;
            }
        }
    } else {
        u16* slab = As + wave * (16 * 72);
        int r0 = brow + wr * 64, c0 = bcol + wc * 64;
        int row = lane >> 2, colb = (lane & 3) * 8;
        #pragma unroll
        for (int mi = 0; mi < 4; ++mi) {
            #pragma unroll
            for (int ni = 0; ni < 4; ++ni)
                #pragma unroll
                for (int rr = 0; rr < 4; ++rr)
                    slab[(hi * 4 + rr) * 72 + ni * 16 + l15] = f2bf(acc[mi][ni][rr]);
            #pragma unroll
            for (int v = 0; v < 2; ++v) {
                short8 val = *(const short8*)&slab[row * 72 + colb + v * 32];
                *(short8*)((u16*)C + (size_t)(r0 + mi * 16 + row) * N + c0 + colb + v * 32) = val;
            }
        }
    }
}

// ---------------- gate slice: ls[j] = logsigmoid(xg1·W2[:,cc+j] + b2)/16, j=0..7 ----------------
__device__ __forceinline__ void gate_z8(const u16* __restrict__ xg,
                                        const float* __restrict__ W2,
                                        const float* __restrict__ b2,
                                        int cc, float* out8) {
    short8 x0 = *(const short8*)xg;
    short8 x1 = *(const short8*)(xg + 8);
    float z[8];
    float4 z0 = *(const float4*)(b2 + cc);
    float4 z1 = *(const float4*)(b2 + cc + 4);
    z[0]=z0.x; z[1]=z0.y; z[2]=z0.z; z[3]=z0.w;
    z[4]=z1.x; z[5]=z1.y; z[6]=z1.z; z[7]=z1.w;
    #pragma unroll
    for (int u = 0; u < 16; ++u) {
        float xu = bf2f((u16)(u < 8 ? x0[u] : x1[u - 8]));
        const float4 w0 = *(const float4*)(W2 + (size_t)u * 512 + cc);
        const float4 w1 = *(const float4*)(W2 + (size_t)u * 512 + cc + 4);
        z[0] += xu * w0.x; z[1] += xu * w0.y; z[2] += xu * w0.z; z[3] += xu * w0.w;
        z[4] += xu * w1.x; z[5] += xu * w1.y; z[6] += xu * w1.z; z[7] += xu * w1.w;
    }
    #pragma unroll
    for (int j = 0; j < 8; ++j) {
        float zz = z[j];
        out8[j] = (fminf(zz, 0.f) - log1pf(expf(-fabsf(zz)))) * 0.0625f;
    }
}

// ---------------- parallel inclusive cumsum over t (64 rows) of gkS[64][36] ----------------
__device__ __forceinline__ void scan64(float (*gkS)[36], float* Ztot, int tid) {
    int wv2 = tid >> 6, ln = tid & 63;
    #pragma unroll
    for (int ii = 0; ii < 8; ++ii) {
        int i = wv2 * 8 + ii;
        float v = gkS[ln][i];
        #pragma unroll
        for (int d = 1; d < 64; d <<= 1) {
            float u = __shfl_up(v, d);
            if (ln >= d) v += u;
        }
        gkS[ln][i] = v;
        if (Ztot && ln == 63) Ztot[i] = v;
    }
}

// -------- phase A (MFMA): gate+cumsum -> qh/kt (bf16); M^T = (kt*EZ)^T @ V -> MT, D --------
__global__ __launch_bounds__(256) void phaseA(const u16* __restrict__ qkvg,
                                              const float* __restrict__ W2,
                                              const float* __restrict__ b2,
                                              u16* __restrict__ qh_ws,
                                              u16* __restrict__ kt_ws,
                                              u16* __restrict__ MT_ws,
                                              float* __restrict__ D_ws) {
    int bh = blockIdx.x >> 6, c = blockIdx.x & 63;
    int b = bh >> 4, h = bh & 15;
    int t0 = b * TT + c * CHUNK;
    __shared__ float gkS[64][36];
    __shared__ u16 kdT_bf[32 * 72];
    __shared__ u16 VT_bf[64 * 72];
    __shared__ float Z[32];
    __shared__ float EZ[32];
    int tid = threadIdx.x;
    int s = tid >> 2, i0 = (tid & 3) << 3;
    {
        float ls[8];
        gate_z8(qkvg + (size_t)(t0 + s) * QSTR + 3072, W2, b2, h * DK + i0, ls);
        #pragma unroll
        for (int jj = 0; jj < 8; ++jj) gkS[s][i0 + jj] = ls[jj];
    }
    short8 qv = *(const short8*)(qkvg + (size_t)(t0 + s) * QSTR + h * DK + i0);
    short8 kv = *(const short8*)(qkvg + (size_t)(t0 + s) * QSTR + 512 + h * DK + i0);
    {
        int j0 = (tid & 3) << 4;
        short8 v0 = *(const short8*)(qkvg + (size_t)(t0 + s) * QSTR + 1024 + h * DV + j0);
        short8 v1 = *(const short8*)(qkvg + (size_t)(t0 + s) * QSTR + 1024 + h * DV + j0 + 8);
        #pragma unroll
        for (int jj = 0; jj < 8; ++jj) {
            VT_bf[(j0 + jj) * 72 + s] = (u16)v0[jj];
            VT_bf[(j0 + 8 + jj) * 72 + s] = (u16)v1[jj];
        }
    }
    __syncthreads();
    scan64(gkS, Z, tid);
    __syncthreads();
    if (tid < 32) {
        float ez = expf(Z[tid]);
        EZ[tid] = ez;
        D_ws[(size_t)(bh * NCH + c) * 32 + tid] = ez;
    }
    __syncthreads();
    // qh = q*exp(S)*SCALE, kt = k*exp(-S) (bf16, coalesced); kd = kt_f * EZ
    {
        short8 qo, ko;
        #pragma unroll
        for (int jj = 0; jj < 8; ++jj) {
            float Sv = gkS[s][i0 + jj];
            float ktf = bf2f((u16)kv[jj]) * expf(fminf(-Sv, 80.f));
            qo[jj] = (short)f2bf(bf2f((u16)qv[jj]) * expf(Sv) * SCALE);
            ko[jj] = (short)f2bf(ktf);
            kdT_bf[(i0 + jj) * 72 + s] = f2bf(ktf * EZ[i0 + jj]);
        }
        *(short8*)(qh_ws + (size_t)(t0 + s) * KD + h * DK + i0) = qo;
        *(short8*)(kt_ws + (size_t)(t0 + s) * KD + h * DK + i0) = ko;
    }
    __syncthreads();
    int wave = tid >> 6, lane = tid & 63, l15 = lane & 15, hi = lane >> 4;
    int it = wave & 1, jp = wave >> 1;
    size_t base = ((size_t)(bh * NCH + c)) * 2048;
    #pragma unroll
    for (int jj2 = 0; jj2 < 2; ++jj2) {
        int jt = jp * 2 + jj2;
        f32x4 mc = (f32x4){0.f, 0.f, 0.f, 0.f};
        #pragma unroll
        for (int kc = 0; kc < 2; ++kc) {
            short8 ak = *(const short8*)&kdT_bf[(it * 16 + l15) * 72 + kc * 32 + hi * 8];
            short8 bv = *(const short8*)&VT_bf[(jt * 16 + l15) * 72 + kc * 32 + hi * 8];
            mc = __builtin_amdgcn_mfma_f32_16x16x32_bf16(ak, bv, mc, 0, 0, 0);
        }
        #pragma unroll
        for (int rr = 0; rr < 4; ++rr)
            MT_ws[base + (size_t)(jt * 16 + l15) * 32 + it * 16 + hi * 4 + rr] = f2bf(mc[rr]);
    }
}

// ---------------- phase B: chunk-state recurrence, 2 elems/thread, unrolled ----------------
__global__ __launch_bounds__(256) void phaseB(const u16* __restrict__ MT_ws,
                                              const float* __restrict__ D_ws,
                                              u16* __restrict__ HT_ws) {
    int idx = (blockIdx.x * 256 + threadIdx.x) * 2;
    int bh = idx >> 11;
    int ji = idx & 2047;
    int i = ji & 31;
    float h0 = 0.f, h1 = 0.f;
    size_t base = (size_t)bh * NCH * 2048 + ji;
    const float* dp = D_ws + (size_t)bh * NCH * 32 + i;
    #pragma unroll 4
    for (int c = 0; c < NCH; ++c) {
        u32 hp = ((u32)f2bf(h0)) | (((u32)f2bf(h1)) << 16);
        *(u32*)(HT_ws + base + (size_t)c * 2048) = hp;
        float d0 = dp[c * 32], d1 = dp[c * 32 + 1];
        u32 mp = *(const u32*)(MT_ws + base + (size_t)c * 2048);
        h0 = h0 * d0 + bf2f((u16)(mp & 0xffff));
        h1 = h1 * d1 + bf2f((u16)(mp >> 16));
    }
}

// ---------- phase C (MFMA): load qh/kt; score->mask->P, O = P@V + qh@H, RMS/swish ----------
__global__ __launch_bounds__(256) void phaseC(const u16* __restrict__ qkvg,
                                              const u16* __restrict__ qh_ws,
                                              const u16* __restrict__ kt_ws,
                                              const u16* __restrict__ HT_ws,
                                              const float* __restrict__ gnw,
                                              u16* __restrict__ o_n) {
    int bh = blockIdx.x >> 6, c = blockIdx.x & 63;
    int b = bh >> 4, h = bh & 15;
    int t0 = b * TT + c * CHUNK;
    __shared__ u16 P_bf[64 * 72];
    __shared__ u16 qh_bf[64 * 40];
    __shared__ u16 kt_bf[64 * 40];
    __shared__ u16 VT_bf[64 * 72];
    __shared__ u16 Ht_bf[64 * 40];
    int tid = threadIdx.x;
    int s = tid >> 2, i0 = (tid & 3) << 3;
    // qh/kt precomputed by phaseA (bit-identical values)
    {
        short8 qo = *(const short8*)(qh_ws + (size_t)(t0 + s) * KD + h * DK + i0);
        short8 ko = *(const short8*)(kt_ws + (size_t)(t0 + s) * KD + h * DK + i0);
        *(short8*)&qh_bf[s * 40 + i0] = qo;
        *(short8*)&kt_bf[s * 40 + i0] = ko;
    }
    {
        int j0 = (tid & 3) << 4;
        short8 v0 = *(const short8*)(qkvg + (size_t)(t0 + s) * QSTR + 1024 + h * DV + j0);
        short8 v1 = *(const short8*)(qkvg + (size_t)(t0 + s) * QSTR + 1024 + h * DV + j0 + 8);
        #pragma unroll
        for (int jj = 0; jj < 8; ++jj) {
            VT_bf[(j0 + jj) * 72 + s] = (u16)v0[jj];
            VT_bf[(j0 + 8 + jj) * 72 + s] = (u16)v1[jj];
        }
    }
    {
        const u16* hp = HT_ws + ((size_t)(bh * NCH + c)) * 2048 + tid * 8;
        short8 hv = *(const short8*)hp;
        int j = tid >> 2, ii0 = (tid & 3) << 3;
        *(short8*)&Ht_bf[j * 40 + ii0] = hv;
    }
    __syncthreads();
    int wave = tid >> 6, lane = tid & 63, l15 = lane & 15, hi = lane >> 4;
    int w = wave;
    short8 aq = *(const short8*)&qh_bf[(w * 16 + l15) * 40 + hi * 8];
    #pragma unroll
    for (int sn = 0; sn < 4; ++sn) {
        f32x4 sc = (f32x4){0.f, 0.f, 0.f, 0.f};
        if (sn <= w) {
            short8 bk = *(const short8*)&kt_bf[(sn * 16 + l15) * 40 + hi * 8];
            sc = __builtin_amdgcn_mfma_f32_16x16x32_bf16(aq, bk, sc, 0, 0, 0);
        }
        #pragma unroll
        for (int rr = 0; rr < 4; ++rr) {
            float val = sc[rr];
            if (sn > w || (sn == w && l15 > hi * 4 + rr)) val = 0.f;
            P_bf[(w * 16 + hi * 4 + rr) * 72 + sn * 16 + l15] = f2bf(val);
        }
    }
    __syncthreads();
    f32x4 acc[4];
    #pragma unroll
    for (int jn = 0; jn < 4; ++jn) {
        f32x4 a = (f32x4){0.f, 0.f, 0.f, 0.f};
        short8 bhf = *(const short8*)&Ht_bf[(jn * 16 + l15) * 40 + hi * 8];
        acc[jn] = __builtin_amdgcn_mfma_f32_16x16x32_bf16(aq, bhf, a, 0, 0, 0);
    }
    int nkc = (w < 2) ? 1 : 2;
    for (int kc = 0; kc < nkc; ++kc) {
        short8 ap = *(const short8*)&P_bf[(w * 16 + l15) * 72 + kc * 32 + hi * 8];
        #pragma unroll
        for (int jn = 0; jn < 4; ++jn) {
            short8 bv = *(const short8*)&VT_bf[(jn * 16 + l15) * 72 + kc * 32 + hi * 8];
            acc[jn] = __builtin_amdgcn_mfma_f32_16x16x32_bf16(ap, bv, acc[jn], 0, 0, 0);
        }
    }
    #pragma unroll
    for (int rr = 0; rr < 4; ++rr) {
        float sum2 = 0.f;
        #pragma unroll
        for (int jn = 0; jn < 4; ++jn) sum2 += acc[jn][rr] * acc[jn][rr];
        sum2 += __shfl_xor(sum2, 1);
        sum2 += __shfl_xor(sum2, 2);
        sum2 += __shfl_xor(sum2, 4);
        sum2 += __shfl_xor(sum2, 8);
        float rms = rsqrtf(sum2 * (1.f / 64.f) + 1e-5f);
        int t = w * 16 + hi * 4 + rr;
        #pragma unroll
        for (int jn = 0; jn < 4; ++jn) {
            int j = jn * 16 + l15;
            float g = bf2f(qkvg[(size_t)(t0 + t) * QSTR + 2048 + h * DV + j]);
            float sw = g / (1.f + expf(-g));
            float o = acc[jn][rr] * rms * gnw[j] * sw;
            o_n[(size_t)(t0 + t) * 1024 + h * DV + j] = f2bf(o);
        }
    }
}

// ---------------- launch ----------------
extern "C" void kernel_launch(void* const* d_in, const int* in_sizes, int n_in,
                              void* d_out, int out_size, void* d_ws, size_t ws_size,
                              hipStream_t stream) {
    const float* x    = (const float*)d_in[0];
    const float* Wq   = (const float*)d_in[1];
    const float* Wk   = (const float*)d_in[2];
    const float* Wv   = (const float*)d_in[3];
    const float* Wgk1 = (const float*)d_in[4];
    const float* Wgk2 = (const float*)d_in[5];
    const float* bgk2 = (const float*)d_in[6];
    const float* Wg   = (const float*)d_in[7];
    const float* gnw  = (const float*)d_in[8];
    const float* Wo   = (const float*)d_in[9];

    char* ws = (char*)d_ws;
    size_t off = 0;
    u16* xb      = (u16*)(ws + off); off += (size_t)MROWS * 1024 * 2;          // 16.8 MB
    u16* Wall    = (u16*)(ws + off); off += (size_t)4352 * 1024 * 2;           // 8.9 MB (WcatT | WoT)
    u16* qkvg    = (u16*)(ws + off); off += (size_t)MROWS * QSTR * 2;          // 54.5 MB
    u16* qh_ws   = (u16*)(ws + off); off += (size_t)MROWS * KD * 2;            // 8.4 MB (bf16)
    u16* kt_ws   = (u16*)(ws + off); off += (size_t)MROWS * KD * 2;            // 8.4 MB (bf16)
    u16* MT_ws   = (u16*)(ws + off); off += (size_t)NBH * NCH * 2048 * 2;      // 8.4 MB (bf16)
    float* D_ws  = (float*)(ws + off); off += (size_t)NBH * NCH * 32 * 4;      // 0.26 MB
    u16* HT_ws   = (u16*)(ws + off); off += (size_t)NBH * NCH * 2048 * 2;      // 8.4 MB (bf16)
    u16* o_n     = (u16*)(ws + off); off += (size_t)MROWS * 1024 * 2;          // 16.8 MB
    u16* WcatT   = Wall;
    u16* WoT     = Wall + (size_t)3328 * 1024;

    prep_fused<<<8192 + 136 * 32, 256, 0, stream>>>(x, xb, Wq, Wk, Wv, Wg, Wgk1, Wo, Wall);
    gemm8<1><<<416, 512, 0, stream>>>(xb, WcatT, qkvg, MROWS, QSTR, 1024, 13);
    phaseA<<<NBH * NCH, 256, 0, stream>>>(qkvg, Wgk2, bgk2, qh_ws, kt_ws, MT_ws, D_ws);
    phaseB<<<128, 256, 0, stream>>>(MT_ws, D_ws, HT_ws);
    phaseC<<<NBH * NCH, 256, 0, stream>>>(qkvg, qh_ws, kt_ws, HT_ws, gnw, o_n);
    gemm_sb<0><<<8 * 64, 256, 0, stream>>>(o_n, WoT, d_out, MROWS, 1024, 1024, 8);
}